// Round 1
// baseline (1360.311 us; speedup 1.0000x reference)
//
#include <hip/hip_runtime.h>
#include <hip/hip_bf16.h>
#include <math.h>

#define NN 50000
#define NE 800000

// ---------------- init: deg=1 (self loop), zero stat scalars ----------------
__global__ __launch_bounds__(256) void init_k(float* __restrict__ deg, float* __restrict__ scal, int n){
  int i = blockIdx.x*256 + threadIdx.x;
  if (i < n) deg[i] = 1.0f;
  if (blockIdx.x == 0 && threadIdx.x < 16) scal[threadIdx.x] = 0.0f;
}

// ---------------- fused MLP: h2 = relu(relu(x@w1+b1)@w2+b2), 16 nodes/block ----------------
__global__ __launch_bounds__(256) void mlp12_k(const float* __restrict__ x, const float* __restrict__ w1,
    const float* __restrict__ b1, const float* __restrict__ w2, const float* __restrict__ b2,
    float* __restrict__ h2, int M){
  __shared__ float xs[16][128];
  __shared__ float h1s[16][512];
  const int m0 = blockIdx.x*16;
  const int t = threadIdx.x;
  // stage x tile (16x128)
  for (int i = t; i < 512; i += 256){
    int row = i >> 5, kq = i & 31;
    float4 v = make_float4(0.f,0.f,0.f,0.f);
    if (m0 + row < M) v = *(const float4*)(x + (size_t)(m0+row)*128 + kq*4);
    *(float4*)&xs[row][kq*4] = v;
  }
  __syncthreads();
  // h1 (16x512), each thread cols {t, t+256}
  {
    const int c = t;
    float accA[16], accB[16];
    #pragma unroll
    for (int m=0;m<16;m++){ accA[m]=0.f; accB[m]=0.f; }
    for (int k0=0;k0<128;k0+=4){
      float wA[4], wB[4];
      #pragma unroll
      for (int j=0;j<4;j++){ wA[j] = w1[(k0+j)*512 + c]; wB[j] = w1[(k0+j)*512 + c + 256]; }
      #pragma unroll
      for (int m=0;m<16;m++){
        float4 xv = *(const float4*)&xs[m][k0];
        accA[m] += xv.x*wA[0] + xv.y*wA[1] + xv.z*wA[2] + xv.w*wA[3];
        accB[m] += xv.x*wB[0] + xv.y*wB[1] + xv.z*wB[2] + xv.w*wB[3];
      }
    }
    float bA = b1[c], bB = b1[c+256];
    #pragma unroll
    for (int m=0;m<16;m++){
      h1s[m][c]     = fmaxf(accA[m]+bA, 0.f);
      h1s[m][c+256] = fmaxf(accB[m]+bB, 0.f);
    }
  }
  __syncthreads();
  // h2 (16x64): thread -> col c=t&63, rows g*4..g*4+3
  {
    const int c = t & 63, g = t >> 6;
    float a[4] = {0.f,0.f,0.f,0.f};
    for (int k0=0;k0<512;k0+=4){
      float wv[4];
      #pragma unroll
      for (int j=0;j<4;j++) wv[j] = w2[(k0+j)*64 + c];
      #pragma unroll
      for (int i=0;i<4;i++){
        float4 hv = *(const float4*)&h1s[g*4+i][k0];
        a[i] += hv.x*wv[0] + hv.y*wv[1] + hv.z*wv[2] + hv.w*wv[3];
      }
    }
    float bb = b2[c];
    #pragma unroll
    for (int i=0;i<4;i++){
      int gm = m0 + g*4 + i;
      if (gm < M) h2[(size_t)gm*64 + c] = fmaxf(a[i]+bb, 0.f);
    }
  }
}

// ---------------- generic tiled fp32 GEMM, 64x64 tile, epilogue variants ----------------
// C = EPI( A[MxK] @ B[KxN] )
// PRELU2: B' = relu(2*B) on load.  RESID: v = beta*acc + (1-beta)*extra[m][n].
template<bool BIAS, bool RELU, bool PRELU2, bool RESID>
__global__ __launch_bounds__(256) void gemm_k(const float* __restrict__ A, const float* __restrict__ B,
    const float* __restrict__ bias, const float* __restrict__ extra, float* __restrict__ C,
    int M, int N, int K, float beta){
  __shared__ float As[16][68];
  __shared__ float Bs[16][68];
  const int n0 = blockIdx.x*64, m0 = blockIdx.y*64;
  const int t = threadIdx.x;
  const int tx = t & 15, ty = t >> 4;
  float acc[4][4] = {{0.f}};
  for (int k0 = 0; k0 < K; k0 += 16){
    { // A tile 64x16 -> transposed into As[k][m]
      int row = t >> 2, kq = t & 3;
      int gm = m0 + row;
      float4 a4 = make_float4(0.f,0.f,0.f,0.f);
      if (gm < M) a4 = *(const float4*)(A + (size_t)gm*K + k0 + kq*4);
      As[kq*4+0][row] = a4.x; As[kq*4+1][row] = a4.y;
      As[kq*4+2][row] = a4.z; As[kq*4+3][row] = a4.w;
    }
    { // B tile 16x64
      int kk = t >> 4, nq = t & 15;
      float4 b4 = *(const float4*)(B + (size_t)(k0+kk)*N + n0 + nq*4);
      if (PRELU2){
        b4.x = fmaxf(2.f*b4.x, 0.f); b4.y = fmaxf(2.f*b4.y, 0.f);
        b4.z = fmaxf(2.f*b4.z, 0.f); b4.w = fmaxf(2.f*b4.w, 0.f);
      }
      *(float4*)&Bs[kk][nq*4] = b4;
    }
    __syncthreads();
    #pragma unroll
    for (int kk=0; kk<16; kk++){
      float4 a4 = *(const float4*)&As[kk][ty*4];
      float4 b4 = *(const float4*)&Bs[kk][tx*4];
      acc[0][0] += a4.x*b4.x; acc[0][1] += a4.x*b4.y; acc[0][2] += a4.x*b4.z; acc[0][3] += a4.x*b4.w;
      acc[1][0] += a4.y*b4.x; acc[1][1] += a4.y*b4.y; acc[1][2] += a4.y*b4.z; acc[1][3] += a4.y*b4.w;
      acc[2][0] += a4.z*b4.x; acc[2][1] += a4.z*b4.y; acc[2][2] += a4.z*b4.z; acc[2][3] += a4.z*b4.w;
      acc[3][0] += a4.w*b4.x; acc[3][1] += a4.w*b4.y; acc[3][2] += a4.w*b4.z; acc[3][3] += a4.w*b4.w;
    }
    __syncthreads();
  }
  const int nc = n0 + tx*4;
  float4 bb = make_float4(0.f,0.f,0.f,0.f);
  if (BIAS) bb = *(const float4*)(bias + nc);
  #pragma unroll
  for (int i=0;i<4;i++){
    int gm = m0 + ty*4 + i;
    if (gm >= M) continue;
    float4 v = make_float4(acc[i][0], acc[i][1], acc[i][2], acc[i][3]);
    if (RESID){
      float4 ex = *(const float4*)(extra + (size_t)gm*N + nc);
      float ob = 1.f - beta;
      v.x = beta*v.x + ob*ex.x; v.y = beta*v.y + ob*ex.y;
      v.z = beta*v.z + ob*ex.z; v.w = beta*v.w + ob*ex.w;
    }
    if (BIAS){ v.x += bb.x; v.y += bb.y; v.z += bb.z; v.w += bb.w; }
    if (RELU){
      v.x = fmaxf(v.x,0.f); v.y = fmaxf(v.y,0.f);
      v.z = fmaxf(v.z,0.f); v.w = fmaxf(v.w,0.f);
    }
    *(float4*)(C + (size_t)gm*N + nc) = v;
  }
}

// ---------------- ew: wave-per-edge dot(logits[row], logitsP[col]) + stats ----------------
__global__ __launch_bounds__(256) void ew_k(const float* __restrict__ lg, const float* __restrict__ lgp,
    const int* __restrict__ row, const int* __restrict__ col,
    float* __restrict__ ew, float* __restrict__ scal, int E){
  const int lane = threadIdx.x & 63, wid = threadIdx.x >> 6;
  const int gw = blockIdx.x*4 + wid;
  const int W = gridDim.x*4;
  float s = 0.f, ss = 0.f;
  for (int e = gw; e < E; e += W){
    int r = row[e], c = col[e];
    float v = lg[(size_t)r*64 + lane] * lgp[(size_t)c*64 + lane];
    #pragma unroll
    for (int off=32; off; off>>=1) v += __shfl_xor(v, off, 64);
    if (lane == 0){ ew[e] = v; s += v; ss += v*v; }
  }
  __shared__ float ls[4], lss[4];
  if (lane == 0){ ls[wid] = s; lss[wid] = ss; }
  __syncthreads();
  if (threadIdx.x == 0){
    atomicAdd(&scal[0], ls[0]+ls[1]+ls[2]+ls[3]);
    atomicAdd(&scal[1], lss[0]+lss[1]+lss[2]+lss[3]);
  }
}

__global__ void finalize_k(float* scal, int E){
  double sum = (double)scal[0], sumsq = (double)scal[1];
  double mean = sum / (double)E;
  double var  = (sumsq - sum*sum/(double)E) / (double)(E-1);
  scal[2] = (float)mean;
  scal[3] = (float)sqrt(1e-4 / var);
}

// normalize ew, accumulate degree at col
__global__ __launch_bounds__(256) void ewnorm_k(float* __restrict__ ew, const int* __restrict__ col,
    float* __restrict__ deg, const float* __restrict__ scal, int E){
  int e = blockIdx.x*256 + threadIdx.x;
  if (e < E){
    float w = (ew[e] - scal[2]) * scal[3] + 1.0f;
    ew[e] = w;
    atomicAdd(&deg[col[e]], w);
  }
}

__global__ __launch_bounds__(256) void dinv_k(float* __restrict__ deg, int n){
  int i = blockIdx.x*256 + threadIdx.x;
  if (i < n){ float d = deg[i]; deg[i] = (d > 0.f) ? rsqrtf(d) : 0.f; }
}

// edge norm = dinv[r]*w*dinv[c]  (in place over ew)
__global__ __launch_bounds__(256) void norm_k(float* __restrict__ ew, const int* __restrict__ row,
    const int* __restrict__ col, const float* __restrict__ dinv, int E){
  int e = blockIdx.x*256 + threadIdx.x;
  if (e < E) ew[e] = dinv[row[e]] * ew[e] * dinv[col[e]];
}

// agg init: self-loop term dinv[i]^2 * h[i]
__global__ __launch_bounds__(256) void agginit_k(float* __restrict__ agg, const float* __restrict__ h,
    const float* __restrict__ dinv, int total){
  int idx = blockIdx.x*256 + threadIdx.x;
  if (idx < total){
    int i = idx >> 7;
    float d = dinv[i];
    agg[idx] = d*d*h[idx];
  }
}

// agg scatter: agg[c] += norm[e]*h[r], 2 edges per block, 128 ch each
__global__ __launch_bounds__(256) void aggedge_k(const float* __restrict__ h, const float* __restrict__ nrm,
    const int* __restrict__ row, const int* __restrict__ col, float* __restrict__ agg, int E){
  int le = threadIdx.x >> 7, k = threadIdx.x & 127;
  int e = blockIdx.x*2 + le;
  if (e < E){
    int r = row[e], c = col[e];
    atomicAdd(&agg[(size_t)c*128 + k], nrm[e] * h[(size_t)r*128 + k]);
  }
}

extern "C" void kernel_launch(void* const* d_in, const int* in_sizes, int n_in,
                              void* d_out, int out_size, void* d_ws, size_t ws_size,
                              hipStream_t stream){
  const float* x      = (const float*)d_in[0];
  const int*   ei     = (const int*)  d_in[1];
  const float* w1     = (const float*)d_in[2];
  const float* b1     = (const float*)d_in[3];
  const float* w2     = (const float*)d_in[4];
  const float* b2     = (const float*)d_in[5];
  const float* w3     = (const float*)d_in[6];
  const float* b3     = (const float*)d_in[7];
  const float* pars   = (const float*)d_in[8];   // [2,64,64], layer 0 used
  const float* lin0w  = (const float*)d_in[9];
  const float* lin0b  = (const float*)d_in[10];
  const float* lin1w  = (const float*)d_in[11];
  const float* lin1b  = (const float*)d_in[12];
  const float* cw1    = (const float*)d_in[13];
  float* out          = (float*)d_out;

  float* ws = (float*)d_ws;
  // workspace layout (element offsets)
  float* h2      = ws + 0;                 //  3,200,000
  float* logits  = ws + 3200000;           //  3,200,000
  float* logitsP = ws + 6400000;           //  3,200,000
  float* ew      = ws + 9600000;           //    800,000
  float* deg     = ws + 10400000;          //     50,000 (becomes dinv)
  float* scal    = ws + 10450048;          //         16
  float* bufA    = ws + 10450176;          //  6,400,000
  float* bufB    = ws + 16850176;          //  6,400,000
  float* bufC    = ws + 23250176;          //  6,400,000  (end ~118.6 MB)

  const int Mn = NN, E = NE;
  const int* erow = ei;
  const int* ecol = ei + E;
  const float beta0 = 0.69314718055994530942f;  // ln(2)
  const float beta1 = 0.40546510810816438198f;  // ln(1.5)

  // 1) init deg=1, scalars=0
  init_k<<<(Mn+255)/256, 256, 0, stream>>>(deg, scal, Mn);
  // 2) fused MLP -> h2
  mlp12_k<<<(Mn+15)/16, 256, 0, stream>>>(x, w1, b1, w2, b2, h2, Mn);
  // 3) logits = h2@w3 + b3
  dim3 g64(1, (Mn+63)/64);
  gemm_k<true,false,false,false><<<g64, 256, 0, stream>>>(h2, w3, b3, nullptr, logits, Mn, 64, 64, 0.f);
  // 4) logitsP = logits @ relu(2*parsing[0])
  gemm_k<false,false,true,false><<<g64, 256, 0, stream>>>(logits, pars, nullptr, nullptr, logitsP, Mn, 64, 64, 0.f);
  // 5) ew + stats
  ew_k<<<2048, 256, 0, stream>>>(logits, logitsP, erow, ecol, ew, scal, E);
  finalize_k<<<1, 1, 0, stream>>>(scal, E);
  // 6) normalize ew, degree accumulation
  ewnorm_k<<<(E+255)/256, 256, 0, stream>>>(ew, ecol, deg, scal, E);
  dinv_k<<<(Mn+255)/256, 256, 0, stream>>>(deg, Mn);
  norm_k<<<(E+255)/256, 256, 0, stream>>>(ew, erow, ecol, deg, E);
  // 7) x0 = relu(x@lin0w + lin0b) -> bufA
  dim3 g128(2, (Mn+63)/64);
  gemm_k<true,true,false,false><<<g128, 256, 0, stream>>>(x, lin0w, lin0b, nullptr, bufA, Mn, 128, 128, 0.f);
  // 8) layer 0: agg(bufB) from bufA; hnext(bufC)
  agginit_k<<<(Mn*128+255)/256, 256, 0, stream>>>(bufB, bufA, deg, Mn*128);
  aggedge_k<<<(E+1)/2, 256, 0, stream>>>(bufA, ew, erow, ecol, bufB, E);
  gemm_k<false,true,false,true><<<g128, 256, 0, stream>>>(bufB, cw1, nullptr, bufB, bufC, Mn, 128, 128, beta0);
  // 9) layer 1: agg(bufA) from bufC; hnext(bufB)
  agginit_k<<<(Mn*128+255)/256, 256, 0, stream>>>(bufA, bufC, deg, Mn*128);
  aggedge_k<<<(E+1)/2, 256, 0, stream>>>(bufC, ew, erow, ecol, bufA, E);
  gemm_k<false,true,false,true><<<g128, 256, 0, stream>>>(bufA, cw1 + 128*128, nullptr, bufA, bufB, Mn, 128, 128, beta1);
  // 10) out = bufB @ lin1w + lin1b
  gemm_k<true,false,false,false><<<dim3(1,(Mn+63)/64), 256, 0, stream>>>(bufB, lin1w, lin1b, nullptr, out, Mn, 64, 128, 0.f);
}

// Round 2
// 995.479 us; speedup vs baseline: 1.3665x; 1.3665x over previous
//
#include <hip/hip_runtime.h>
#include <hip/hip_bf16.h>
#include <math.h>

#define NN 50000
#define NE 800000

// ---------------- init: deg=1 (self loop), zero stat scalars ----------------
__global__ __launch_bounds__(256) void init_k(float* __restrict__ deg, float* __restrict__ scal, int n){
  int i = blockIdx.x*256 + threadIdx.x;
  if (i < n) deg[i] = 1.0f;
  if (blockIdx.x == 0 && threadIdx.x < 16) scal[threadIdx.x] = 0.0f;
}

__global__ __launch_bounds__(256) void zero_cnt_k(int* __restrict__ cnt, int n){
  int i = blockIdx.x*256 + threadIdx.x;
  if (i < n) cnt[i] = 0;
}

// ---------------- fused MLP: h2 = relu(relu(x@w1+b1)@w2+b2), 16 nodes/block ----------------
__global__ __launch_bounds__(256) void mlp12_k(const float* __restrict__ x, const float* __restrict__ w1,
    const float* __restrict__ b1, const float* __restrict__ w2, const float* __restrict__ b2,
    float* __restrict__ h2, int M){
  __shared__ float xs[16][128];
  __shared__ float h1s[16][512];
  const int m0 = blockIdx.x*16;
  const int t = threadIdx.x;
  for (int i = t; i < 512; i += 256){
    int row = i >> 5, kq = i & 31;
    float4 v = make_float4(0.f,0.f,0.f,0.f);
    if (m0 + row < M) v = *(const float4*)(x + (size_t)(m0+row)*128 + kq*4);
    *(float4*)&xs[row][kq*4] = v;
  }
  __syncthreads();
  {
    const int c = t;
    float accA[16], accB[16];
    #pragma unroll
    for (int m=0;m<16;m++){ accA[m]=0.f; accB[m]=0.f; }
    for (int k0=0;k0<128;k0+=4){
      float wA[4], wB[4];
      #pragma unroll
      for (int j=0;j<4;j++){ wA[j] = w1[(k0+j)*512 + c]; wB[j] = w1[(k0+j)*512 + c + 256]; }
      #pragma unroll
      for (int m=0;m<16;m++){
        float4 xv = *(const float4*)&xs[m][k0];
        accA[m] += xv.x*wA[0] + xv.y*wA[1] + xv.z*wA[2] + xv.w*wA[3];
        accB[m] += xv.x*wB[0] + xv.y*wB[1] + xv.z*wB[2] + xv.w*wB[3];
      }
    }
    float bA = b1[c], bB = b1[c+256];
    #pragma unroll
    for (int m=0;m<16;m++){
      h1s[m][c]     = fmaxf(accA[m]+bA, 0.f);
      h1s[m][c+256] = fmaxf(accB[m]+bB, 0.f);
    }
  }
  __syncthreads();
  {
    const int c = t & 63, g = t >> 6;
    float a[4] = {0.f,0.f,0.f,0.f};
    for (int k0=0;k0<512;k0+=4){
      float wv[4];
      #pragma unroll
      for (int j=0;j<4;j++) wv[j] = w2[(k0+j)*64 + c];
      #pragma unroll
      for (int i=0;i<4;i++){
        float4 hv = *(const float4*)&h1s[g*4+i][k0];
        a[i] += hv.x*wv[0] + hv.y*wv[1] + hv.z*wv[2] + hv.w*wv[3];
      }
    }
    float bb = b2[c];
    #pragma unroll
    for (int i=0;i<4;i++){
      int gm = m0 + g*4 + i;
      if (gm < M) h2[(size_t)gm*64 + c] = fmaxf(a[i]+bb, 0.f);
    }
  }
}

// ---------------- generic tiled fp32 GEMM, 64x64 tile, epilogue variants ----------------
template<bool BIAS, bool RELU, bool PRELU2, bool RESID>
__global__ __launch_bounds__(256) void gemm_k(const float* __restrict__ A, const float* __restrict__ B,
    const float* __restrict__ bias, const float* __restrict__ extra, float* __restrict__ C,
    int M, int N, int K, float beta){
  __shared__ float As[16][68];
  __shared__ float Bs[16][68];
  const int n0 = blockIdx.x*64, m0 = blockIdx.y*64;
  const int t = threadIdx.x;
  const int tx = t & 15, ty = t >> 4;
  float acc[4][4] = {{0.f}};
  for (int k0 = 0; k0 < K; k0 += 16){
    {
      int row = t >> 2, kq = t & 3;
      int gm = m0 + row;
      float4 a4 = make_float4(0.f,0.f,0.f,0.f);
      if (gm < M) a4 = *(const float4*)(A + (size_t)gm*K + k0 + kq*4);
      As[kq*4+0][row] = a4.x; As[kq*4+1][row] = a4.y;
      As[kq*4+2][row] = a4.z; As[kq*4+3][row] = a4.w;
    }
    {
      int kk = t >> 4, nq = t & 15;
      float4 b4 = *(const float4*)(B + (size_t)(k0+kk)*N + n0 + nq*4);
      if (PRELU2){
        b4.x = fmaxf(2.f*b4.x, 0.f); b4.y = fmaxf(2.f*b4.y, 0.f);
        b4.z = fmaxf(2.f*b4.z, 0.f); b4.w = fmaxf(2.f*b4.w, 0.f);
      }
      *(float4*)&Bs[kk][nq*4] = b4;
    }
    __syncthreads();
    #pragma unroll
    for (int kk=0; kk<16; kk++){
      float4 a4 = *(const float4*)&As[kk][ty*4];
      float4 b4 = *(const float4*)&Bs[kk][tx*4];
      acc[0][0] += a4.x*b4.x; acc[0][1] += a4.x*b4.y; acc[0][2] += a4.x*b4.z; acc[0][3] += a4.x*b4.w;
      acc[1][0] += a4.y*b4.x; acc[1][1] += a4.y*b4.y; acc[1][2] += a4.y*b4.z; acc[1][3] += a4.y*b4.w;
      acc[2][0] += a4.z*b4.x; acc[2][1] += a4.z*b4.y; acc[2][2] += a4.z*b4.z; acc[2][3] += a4.z*b4.w;
      acc[3][0] += a4.w*b4.x; acc[3][1] += a4.w*b4.y; acc[3][2] += a4.w*b4.z; acc[3][3] += a4.w*b4.w;
    }
    __syncthreads();
  }
  const int nc = n0 + tx*4;
  float4 bb = make_float4(0.f,0.f,0.f,0.f);
  if (BIAS) bb = *(const float4*)(bias + nc);
  #pragma unroll
  for (int i=0;i<4;i++){
    int gm = m0 + ty*4 + i;
    if (gm >= M) continue;
    float4 v = make_float4(acc[i][0], acc[i][1], acc[i][2], acc[i][3]);
    if (RESID){
      float4 ex = *(const float4*)(extra + (size_t)gm*N + nc);
      float ob = 1.f - beta;
      v.x = beta*v.x + ob*ex.x; v.y = beta*v.y + ob*ex.y;
      v.z = beta*v.z + ob*ex.z; v.w = beta*v.w + ob*ex.w;
    }
    if (BIAS){ v.x += bb.x; v.y += bb.y; v.z += bb.z; v.w += bb.w; }
    if (RELU){
      v.x = fmaxf(v.x,0.f); v.y = fmaxf(v.y,0.f);
      v.z = fmaxf(v.z,0.f); v.w = fmaxf(v.w,0.f);
    }
    *(float4*)(C + (size_t)gm*N + nc) = v;
  }
}

// ---------------- ew: wave-per-edge dot(logits[row], logitsP[col]) + stats ----------------
__global__ __launch_bounds__(256) void ew_k(const float* __restrict__ lg, const float* __restrict__ lgp,
    const int* __restrict__ row, const int* __restrict__ col,
    float* __restrict__ ew, float* __restrict__ scal, int E){
  const int lane = threadIdx.x & 63, wid = threadIdx.x >> 6;
  const int gw = blockIdx.x*4 + wid;
  const int W = gridDim.x*4;
  float s = 0.f, ss = 0.f;
  for (int e = gw; e < E; e += W){
    int r = row[e], c = col[e];
    float v = lg[(size_t)r*64 + lane] * lgp[(size_t)c*64 + lane];
    #pragma unroll
    for (int off=32; off; off>>=1) v += __shfl_xor(v, off, 64);
    if (lane == 0){ ew[e] = v; s += v; ss += v*v; }
  }
  __shared__ float ls[4], lss[4];
  if (lane == 0){ ls[wid] = s; lss[wid] = ss; }
  __syncthreads();
  if (threadIdx.x == 0){
    atomicAdd(&scal[0], ls[0]+ls[1]+ls[2]+ls[3]);
    atomicAdd(&scal[1], lss[0]+lss[1]+lss[2]+lss[3]);
  }
}

__global__ void finalize_k(float* scal, int E){
  double sum = (double)scal[0], sumsq = (double)scal[1];
  double mean = sum / (double)E;
  double var  = (sumsq - sum*sum/(double)E) / (double)(E-1);
  scal[2] = (float)mean;
  scal[3] = (float)sqrt(1e-4 / var);
}

// normalize ew, accumulate float degree at col, int count at col (for CSR)
__global__ __launch_bounds__(256) void ewnorm_k(float* __restrict__ ew, const int* __restrict__ col,
    float* __restrict__ deg, int* __restrict__ cnt, const float* __restrict__ scal, int E){
  int e = blockIdx.x*256 + threadIdx.x;
  if (e < E){
    float w = (ew[e] - scal[2]) * scal[3] + 1.0f;
    ew[e] = w;
    int c = col[e];
    atomicAdd(&deg[c], w);
    atomicAdd(&cnt[c], 1);
  }
}

__global__ __launch_bounds__(256) void dinv_k(float* __restrict__ deg, int n){
  int i = blockIdx.x*256 + threadIdx.x;
  if (i < n){ float d = deg[i]; deg[i] = (d > 0.f) ? rsqrtf(d) : 0.f; }
}

// single-block exclusive scan over cnt -> off[0..n], cursor copy
__global__ __launch_bounds__(1024) void scan_k(const int* __restrict__ cnt, int* __restrict__ off,
    int* __restrict__ cursor, int n){
  __shared__ int sdata[1024];
  __shared__ int carry;
  if (threadIdx.x == 0) carry = 0;
  __syncthreads();
  for (int base = 0; base < n; base += 1024){
    int i = base + threadIdx.x;
    int v = (i < n) ? cnt[i] : 0;
    sdata[threadIdx.x] = v;
    __syncthreads();
    #pragma unroll
    for (int s = 1; s < 1024; s <<= 1){
      int t = 0;
      if ((int)threadIdx.x >= s) t = sdata[threadIdx.x - s];
      __syncthreads();
      sdata[threadIdx.x] += t;
      __syncthreads();
    }
    int excl = sdata[threadIdx.x] - v + carry;
    if (i < n){ off[i] = excl; cursor[i] = excl; }
    __syncthreads();
    if (threadIdx.x == 1023) carry += sdata[1023];
    __syncthreads();
  }
  if (threadIdx.x == 0) off[n] = carry;
}

// bucket edges by destination; store src and final edge weight dinv[r]*w*dinv[c]
__global__ __launch_bounds__(256) void scatter_k(const int* __restrict__ row, const int* __restrict__ col,
    const float* __restrict__ ew, const float* __restrict__ dinv,
    int* __restrict__ cursor, int* __restrict__ csr_src, float* __restrict__ csr_w, int E){
  int e = blockIdx.x*256 + threadIdx.x;
  if (e < E){
    int r = row[e], c = col[e];
    int slot = atomicAdd(&cursor[c], 1);
    csr_src[slot] = r;
    csr_w[slot]  = dinv[r] * ew[e] * dinv[c];
  }
}

// CSR gather aggregation: agg[n] = dinv[n]^2*h[n] + sum_j w[j]*h[src[j]], 2 nodes/block
__global__ __launch_bounds__(256) void agg_gather_k(const float* __restrict__ h,
    const int* __restrict__ off, const int* __restrict__ src, const float* __restrict__ w,
    const float* __restrict__ dinv, float* __restrict__ agg, int Nn){
  int ln = threadIdx.x >> 7;
  int k  = threadIdx.x & 127;
  int n  = blockIdx.x*2 + ln;
  if (n >= Nn) return;
  float d = dinv[n];
  float acc = d*d*h[(size_t)n*128 + k];
  int s = off[n], e = off[n+1];
  int j = s;
  for (; j + 1 < e; j += 2){
    int r0 = src[j], r1 = src[j+1];
    float w0 = w[j], w1 = w[j+1];
    acc += w0 * h[(size_t)r0*128 + k];
    acc += w1 * h[(size_t)r1*128 + k];
  }
  if (j < e) acc += w[j] * h[(size_t)src[j]*128 + k];
  agg[(size_t)n*128 + k] = acc;
}

extern "C" void kernel_launch(void* const* d_in, const int* in_sizes, int n_in,
                              void* d_out, int out_size, void* d_ws, size_t ws_size,
                              hipStream_t stream){
  const float* x      = (const float*)d_in[0];
  const int*   ei     = (const int*)  d_in[1];
  const float* w1     = (const float*)d_in[2];
  const float* b1     = (const float*)d_in[3];
  const float* w2     = (const float*)d_in[4];
  const float* b2     = (const float*)d_in[5];
  const float* w3     = (const float*)d_in[6];
  const float* b3     = (const float*)d_in[7];
  const float* pars   = (const float*)d_in[8];
  const float* lin0w  = (const float*)d_in[9];
  const float* lin0b  = (const float*)d_in[10];
  const float* lin1w  = (const float*)d_in[11];
  const float* lin1b  = (const float*)d_in[12];
  const float* cw1    = (const float*)d_in[13];
  float* out          = (float*)d_out;

  float* ws = (float*)d_ws;
  // workspace layout (element offsets) — CSR arrays overlay h2's region after
  // h2 is consumed by the logits GEMM.
  float* h2      = ws + 0;                 // 3,200,000 (freed after logits GEMM)
  float* logits  = ws + 3200000;
  float* logitsP = ws + 6400000;
  float* ew      = ws + 9600000;           //   800,000
  float* deg     = ws + 10400000;          //    50,000 (becomes dinv)
  float* scal    = ws + 10450048;          //        16
  float* bufA    = ws + 10450176;          // 6,400,000
  float* bufB    = ws + 16850176;          // 6,400,000
  float* bufC    = ws + 23250176;          // 6,400,000 (end 29,650,176 = same as round 0)
  // CSR overlay on h2 region:
  int*   cnt     = (int*)(ws + 0);         //    50,000
  int*   off     = (int*)(ws + 50048);     //    50,001
  int*   cursor  = (int*)(ws + 100096);    //    50,000
  int*   csr_src = (int*)(ws + 150144);    //   800,000
  float* csr_w   = ws + 950144;            //   800,000 (ends 1,750,144 < 3,200,000)

  const int Mn = NN, E = NE;
  const int* erow = ei;
  const int* ecol = ei + E;
  const float beta0 = 0.69314718055994530942f;  // ln(2)
  const float beta1 = 0.40546510810816438198f;  // ln(1.5)

  // 1) init deg=1, scalars=0
  init_k<<<(Mn+255)/256, 256, 0, stream>>>(deg, scal, Mn);
  // 2) fused MLP -> h2
  mlp12_k<<<(Mn+15)/16, 256, 0, stream>>>(x, w1, b1, w2, b2, h2, Mn);
  // 3) logits = h2@w3 + b3   (h2 free afterwards)
  dim3 g64(1, (Mn+63)/64);
  gemm_k<true,false,false,false><<<g64, 256, 0, stream>>>(h2, w3, b3, nullptr, logits, Mn, 64, 64, 0.f);
  // 4) logitsP = logits @ relu(2*parsing[0]);  zero CSR counts (h2 region now free)
  gemm_k<false,false,true,false><<<g64, 256, 0, stream>>>(logits, pars, nullptr, nullptr, logitsP, Mn, 64, 64, 0.f);
  zero_cnt_k<<<(Mn+255)/256, 256, 0, stream>>>(cnt, Mn);
  // 5) ew + stats
  ew_k<<<2048, 256, 0, stream>>>(logits, logitsP, erow, ecol, ew, scal, E);
  finalize_k<<<1, 1, 0, stream>>>(scal, E);
  // 6) normalize ew, degree (float) + count (int) accumulation; dinv
  ewnorm_k<<<(E+255)/256, 256, 0, stream>>>(ew, ecol, deg, cnt, scal, E);
  dinv_k<<<(Mn+255)/256, 256, 0, stream>>>(deg, Mn);
  // 7) CSR build: scan + bucket scatter (stores final edge weights)
  scan_k<<<1, 1024, 0, stream>>>(cnt, off, cursor, Mn);
  scatter_k<<<(E+255)/256, 256, 0, stream>>>(erow, ecol, ew, deg, cursor, csr_src, csr_w, E);
  // 8) x0 = relu(x@lin0w + lin0b) -> bufA
  dim3 g128(2, (Mn+63)/64);
  gemm_k<true,true,false,false><<<g128, 256, 0, stream>>>(x, lin0w, lin0b, nullptr, bufA, Mn, 128, 128, 0.f);
  // 9) layer 0: gather agg(bufB) from bufA; hnext(bufC)
  agg_gather_k<<<(Mn+1)/2, 256, 0, stream>>>(bufA, off, csr_src, csr_w, deg, bufB, Mn);
  gemm_k<false,true,false,true><<<g128, 256, 0, stream>>>(bufB, cw1, nullptr, bufB, bufC, Mn, 128, 128, beta0);
  // 10) layer 1: gather agg(bufA) from bufC; hnext(bufB)
  agg_gather_k<<<(Mn+1)/2, 256, 0, stream>>>(bufC, off, csr_src, csr_w, deg, bufA, Mn);
  gemm_k<false,true,false,true><<<g128, 256, 0, stream>>>(bufA, cw1 + 128*128, nullptr, bufA, bufB, Mn, 128, 128, beta1);
  // 11) out = bufB @ lin1w + lin1b
  gemm_k<true,false,false,false><<<dim3(1,(Mn+63)/64), 256, 0, stream>>>(bufB, lin1w, lin1b, nullptr, out, Mn, 64, 128, 0.f);
}

// Round 3
// 815.998 us; speedup vs baseline: 1.6671x; 1.2200x over previous
//
#include <hip/hip_runtime.h>
#include <hip/hip_bf16.h>
#include <math.h>

#define NN 50000
#define NE 800000

typedef __attribute__((ext_vector_type(8))) short bf16x8;
typedef __attribute__((ext_vector_type(4))) float f32x4;

__device__ __forceinline__ short f2bf(float f){
  unsigned u = __float_as_uint(f);
  unsigned r = (u + 0x7fffu + ((u >> 16) & 1u)) >> 16;
  return (short)r;
}

// ---------------- init: deg=1 (self loop), zero stat scalars ----------------
__global__ __launch_bounds__(256) void init_k(float* __restrict__ deg, float* __restrict__ scal, int n){
  int i = blockIdx.x*256 + threadIdx.x;
  if (i < n) deg[i] = 1.0f;
  if (blockIdx.x == 0 && threadIdx.x < 16) scal[threadIdx.x] = 0.0f;
}

__global__ __launch_bounds__(256) void zero_cnt_k(int* __restrict__ cnt, int n){
  int i = blockIdx.x*256 + threadIdx.x;
  if (i < n) cnt[i] = 0;
}

// ---------------- weight prep: transpose + bf16 convert ----------------
// w1t[512][128], w2t[64][512], w3t[64][64], Pt[64][64] (Pt = relu(2*parsing0)^T)
__global__ __launch_bounds__(256) void prep_k(const float* __restrict__ w1,
    const float* __restrict__ w2, const float* __restrict__ w3, const float* __restrict__ pars,
    short* __restrict__ w1t, short* __restrict__ w2t, short* __restrict__ w3t, short* __restrict__ Pt){
  int idx = blockIdx.x*256 + threadIdx.x;
  if (idx < 65536){
    int n = idx >> 7, k = idx & 127;
    w1t[idx] = f2bf(w1[k*512 + n]);
  } else if (idx < 98304){
    int i = idx - 65536; int n = i >> 9, k = i & 511;
    w2t[i] = f2bf(w2[k*64 + n]);
  } else if (idx < 102400){
    int i = idx - 98304; int n = i >> 6, k = i & 63;
    w3t[i] = f2bf(w3[k*64 + n]);
  } else if (idx < 106496){
    int i = idx - 102400; int n = i >> 6, k = i & 63;
    Pt[i] = f2bf(fmaxf(2.f*pars[k*64 + n], 0.f));
  }
}

// ---------------- fused bf16-MFMA MLP chain: x -> h1 -> h2 -> logits -> logitsP ----------------
// 32 rows per block, 4 waves. All intermediates stay in LDS (bf16).
__global__ __launch_bounds__(256) void mlp_mfma_k(
    const float* __restrict__ x,
    const short* __restrict__ w1t, const float* __restrict__ b1,
    const short* __restrict__ w2t, const float* __restrict__ b2,
    const short* __restrict__ w3t, const float* __restrict__ b3,
    const short* __restrict__ Pt,
    float* __restrict__ logits, float* __restrict__ logitsP, int M)
{
  __shared__ short xs [32][136];   // 128 + 8 pad (keeps 16B align, spreads banks)
  __shared__ short h1s[32][520];   // 512 + 8 pad
  __shared__ short h2s[32][72];    //  64 + 8 pad
  __shared__ short lgs[32][72];
  const int t = threadIdx.x;
  const int wave = t >> 6, lane = t & 63;
  const int quad = lane >> 4, l16 = lane & 15;
  const int m0 = blockIdx.x * 32;

  // ---- stage x (fp32 global) -> xs (bf16 LDS), zero-fill OOB rows ----
  for (int task = t; task < 512; task += 256){
    int row = task >> 4, c0 = (task & 15) * 8;
    float4 v0 = make_float4(0,0,0,0), v1 = v0;
    if (m0 + row < M){
      v0 = *(const float4*)(x + (size_t)(m0+row)*128 + c0);
      v1 = *(const float4*)(x + (size_t)(m0+row)*128 + c0 + 4);
    }
    bf16x8 s;
    s[0]=f2bf(v0.x); s[1]=f2bf(v0.y); s[2]=f2bf(v0.z); s[3]=f2bf(v0.w);
    s[4]=f2bf(v1.x); s[5]=f2bf(v1.y); s[6]=f2bf(v1.z); s[7]=f2bf(v1.w);
    *(bf16x8*)&xs[row][c0] = s;
  }
  __syncthreads();

  // ---- Phase 1: h1 = relu(x @ w1 + b1). wave -> cols [wave*128, wave*128+128) ----
  {
    f32x4 acc[2][8];
    #pragma unroll
    for (int mt=0;mt<2;mt++)
      #pragma unroll
      for (int nt=0;nt<8;nt++) acc[mt][nt] = (f32x4){0.f,0.f,0.f,0.f};
    for (int k0 = 0; k0 < 128; k0 += 32){
      bf16x8 a0 = *(const bf16x8*)&xs[l16     ][k0 + quad*8];
      bf16x8 a1 = *(const bf16x8*)&xs[16 + l16][k0 + quad*8];
      #pragma unroll
      for (int nt = 0; nt < 8; nt++){
        int n = wave*128 + nt*16 + l16;
        bf16x8 b = *(const bf16x8*)(w1t + (size_t)n*128 + k0 + quad*8);
        acc[0][nt] = __builtin_amdgcn_mfma_f32_16x16x32_bf16(a0, b, acc[0][nt], 0,0,0);
        acc[1][nt] = __builtin_amdgcn_mfma_f32_16x16x32_bf16(a1, b, acc[1][nt], 0,0,0);
      }
    }
    #pragma unroll
    for (int nt = 0; nt < 8; nt++){
      int n = wave*128 + nt*16 + l16;
      float bb = b1[n];
      #pragma unroll
      for (int mt = 0; mt < 2; mt++){
        #pragma unroll
        for (int r = 0; r < 4; r++){
          int row = mt*16 + quad*4 + r;
          h1s[row][n] = f2bf(fmaxf(acc[mt][nt][r] + bb, 0.f));
        }
      }
    }
  }
  __syncthreads();

  // ---- Phase 2: h2 = relu(h1 @ w2 + b2). wave -> cols [wave*16, wave*16+16) ----
  {
    f32x4 acc[2];
    acc[0] = (f32x4){0.f,0.f,0.f,0.f}; acc[1] = acc[0];
    const int n = wave*16 + l16;
    for (int k0 = 0; k0 < 512; k0 += 32){
      bf16x8 b  = *(const bf16x8*)(w2t + (size_t)n*512 + k0 + quad*8);
      bf16x8 a0 = *(const bf16x8*)&h1s[l16     ][k0 + quad*8];
      bf16x8 a1 = *(const bf16x8*)&h1s[16 + l16][k0 + quad*8];
      acc[0] = __builtin_amdgcn_mfma_f32_16x16x32_bf16(a0, b, acc[0], 0,0,0);
      acc[1] = __builtin_amdgcn_mfma_f32_16x16x32_bf16(a1, b, acc[1], 0,0,0);
    }
    float bb = b2[n];
    #pragma unroll
    for (int mt = 0; mt < 2; mt++)
      #pragma unroll
      for (int r = 0; r < 4; r++)
        h2s[mt*16 + quad*4 + r][n] = f2bf(fmaxf(acc[mt][r] + bb, 0.f));
  }
  __syncthreads();

  // ---- Phase 3: logits = h2 @ w3 + b3. wave -> cols [wave*16, wave*16+16) ----
  {
    f32x4 acc[2];
    acc[0] = (f32x4){0.f,0.f,0.f,0.f}; acc[1] = acc[0];
    const int n = wave*16 + l16;
    for (int k0 = 0; k0 < 64; k0 += 32){
      bf16x8 b  = *(const bf16x8*)(w3t + (size_t)n*64 + k0 + quad*8);
      bf16x8 a0 = *(const bf16x8*)&h2s[l16     ][k0 + quad*8];
      bf16x8 a1 = *(const bf16x8*)&h2s[16 + l16][k0 + quad*8];
      acc[0] = __builtin_amdgcn_mfma_f32_16x16x32_bf16(a0, b, acc[0], 0,0,0);
      acc[1] = __builtin_amdgcn_mfma_f32_16x16x32_bf16(a1, b, acc[1], 0,0,0);
    }
    float bb = b3[n];
    #pragma unroll
    for (int mt = 0; mt < 2; mt++)
      #pragma unroll
      for (int r = 0; r < 4; r++){
        int row = mt*16 + quad*4 + r;
        float v = acc[mt][r] + bb;
        lgs[row][n] = f2bf(v);
        int gm = m0 + row;
        if (gm < M) logits[(size_t)gm*64 + n] = v;
      }
  }
  __syncthreads();

  // ---- Phase 4: logitsP = logits @ relu(2P). wave -> cols [wave*16, wave*16+16) ----
  {
    f32x4 acc[2];
    acc[0] = (f32x4){0.f,0.f,0.f,0.f}; acc[1] = acc[0];
    const int n = wave*16 + l16;
    for (int k0 = 0; k0 < 64; k0 += 32){
      bf16x8 b  = *(const bf16x8*)(Pt + (size_t)n*64 + k0 + quad*8);
      bf16x8 a0 = *(const bf16x8*)&lgs[l16     ][k0 + quad*8];
      bf16x8 a1 = *(const bf16x8*)&lgs[16 + l16][k0 + quad*8];
      acc[0] = __builtin_amdgcn_mfma_f32_16x16x32_bf16(a0, b, acc[0], 0,0,0);
      acc[1] = __builtin_amdgcn_mfma_f32_16x16x32_bf16(a1, b, acc[1], 0,0,0);
    }
    #pragma unroll
    for (int mt = 0; mt < 2; mt++)
      #pragma unroll
      for (int r = 0; r < 4; r++){
        int gm = m0 + mt*16 + quad*4 + r;
        if (gm < M) logitsP[(size_t)gm*64 + n] = acc[mt][r];
      }
  }
}

// ---------------- generic tiled fp32 GEMM, 64x64 tile, epilogue variants ----------------
template<bool BIAS, bool RELU, bool RESID>
__global__ __launch_bounds__(256) void gemm_k(const float* __restrict__ A, const float* __restrict__ B,
    const float* __restrict__ bias, const float* __restrict__ extra, float* __restrict__ C,
    int M, int N, int K, float beta){
  __shared__ float As[16][68];
  __shared__ float Bs[16][68];
  const int n0 = blockIdx.x*64, m0 = blockIdx.y*64;
  const int t = threadIdx.x;
  const int tx = t & 15, ty = t >> 4;
  float acc[4][4] = {{0.f}};
  for (int k0 = 0; k0 < K; k0 += 16){
    {
      int row = t >> 2, kq = t & 3;
      int gm = m0 + row;
      float4 a4 = make_float4(0.f,0.f,0.f,0.f);
      if (gm < M) a4 = *(const float4*)(A + (size_t)gm*K + k0 + kq*4);
      As[kq*4+0][row] = a4.x; As[kq*4+1][row] = a4.y;
      As[kq*4+2][row] = a4.z; As[kq*4+3][row] = a4.w;
    }
    {
      int kk = t >> 4, nq = t & 15;
      float4 b4 = *(const float4*)(B + (size_t)(k0+kk)*N + n0 + nq*4);
      *(float4*)&Bs[kk][nq*4] = b4;
    }
    __syncthreads();
    #pragma unroll
    for (int kk=0; kk<16; kk++){
      float4 a4 = *(const float4*)&As[kk][ty*4];
      float4 b4 = *(const float4*)&Bs[kk][tx*4];
      acc[0][0] += a4.x*b4.x; acc[0][1] += a4.x*b4.y; acc[0][2] += a4.x*b4.z; acc[0][3] += a4.x*b4.w;
      acc[1][0] += a4.y*b4.x; acc[1][1] += a4.y*b4.y; acc[1][2] += a4.y*b4.z; acc[1][3] += a4.y*b4.w;
      acc[2][0] += a4.z*b4.x; acc[2][1] += a4.z*b4.y; acc[2][2] += a4.z*b4.z; acc[2][3] += a4.z*b4.w;
      acc[3][0] += a4.w*b4.x; acc[3][1] += a4.w*b4.y; acc[3][2] += a4.w*b4.z; acc[3][3] += a4.w*b4.w;
    }
    __syncthreads();
  }
  const int nc = n0 + tx*4;
  float4 bb = make_float4(0.f,0.f,0.f,0.f);
  if (BIAS) bb = *(const float4*)(bias + nc);
  #pragma unroll
  for (int i=0;i<4;i++){
    int gm = m0 + ty*4 + i;
    if (gm >= M) continue;
    float4 v = make_float4(acc[i][0], acc[i][1], acc[i][2], acc[i][3]);
    if (RESID){
      float4 ex = *(const float4*)(extra + (size_t)gm*N + nc);
      float ob = 1.f - beta;
      v.x = beta*v.x + ob*ex.x; v.y = beta*v.y + ob*ex.y;
      v.z = beta*v.z + ob*ex.z; v.w = beta*v.w + ob*ex.w;
    }
    if (BIAS){ v.x += bb.x; v.y += bb.y; v.z += bb.z; v.w += bb.w; }
    if (RELU){
      v.x = fmaxf(v.x,0.f); v.y = fmaxf(v.y,0.f);
      v.z = fmaxf(v.z,0.f); v.w = fmaxf(v.w,0.f);
    }
    *(float4*)(C + (size_t)gm*N + nc) = v;
  }
}

// ---------------- ew: wave-per-edge dot(logits[row], logitsP[col]) + stats ----------------
__global__ __launch_bounds__(256) void ew_k(const float* __restrict__ lg, const float* __restrict__ lgp,
    const int* __restrict__ row, const int* __restrict__ col,
    float* __restrict__ ew, float* __restrict__ scal, int E){
  const int lane = threadIdx.x & 63, wid = threadIdx.x >> 6;
  const int gw = blockIdx.x*4 + wid;
  const int W = gridDim.x*4;
  float s = 0.f, ss = 0.f;
  for (int e = gw; e < E; e += W){
    int r = row[e], c = col[e];
    float v = lg[(size_t)r*64 + lane] * lgp[(size_t)c*64 + lane];
    #pragma unroll
    for (int off=32; off; off>>=1) v += __shfl_xor(v, off, 64);
    if (lane == 0){ ew[e] = v; s += v; ss += v*v; }
  }
  __shared__ float ls[4], lss[4];
  if (lane == 0){ ls[wid] = s; lss[wid] = ss; }
  __syncthreads();
  if (threadIdx.x == 0){
    atomicAdd(&scal[0], ls[0]+ls[1]+ls[2]+ls[3]);
    atomicAdd(&scal[1], lss[0]+lss[1]+lss[2]+lss[3]);
  }
}

__global__ void finalize_k(float* scal, int E){
  double sum = (double)scal[0], sumsq = (double)scal[1];
  double mean = sum / (double)E;
  double var  = (sumsq - sum*sum/(double)E) / (double)(E-1);
  scal[2] = (float)mean;
  scal[3] = (float)sqrt(1e-4 / var);
}

// normalize ew, accumulate float degree at col, int count at col (for CSR)
__global__ __launch_bounds__(256) void ewnorm_k(float* __restrict__ ew, const int* __restrict__ col,
    float* __restrict__ deg, int* __restrict__ cnt, const float* __restrict__ scal, int E){
  int e = blockIdx.x*256 + threadIdx.x;
  if (e < E){
    float w = (ew[e] - scal[2]) * scal[3] + 1.0f;
    ew[e] = w;
    int c = col[e];
    atomicAdd(&deg[c], w);
    atomicAdd(&cnt[c], 1);
  }
}

__global__ __launch_bounds__(256) void dinv_k(float* __restrict__ deg, int n){
  int i = blockIdx.x*256 + threadIdx.x;
  if (i < n){ float d = deg[i]; deg[i] = (d > 0.f) ? rsqrtf(d) : 0.f; }
}

// single-block exclusive scan over cnt -> off[0..n], cursor copy
__global__ __launch_bounds__(1024) void scan_k(const int* __restrict__ cnt, int* __restrict__ off,
    int* __restrict__ cursor, int n){
  __shared__ int sdata[1024];
  __shared__ int carry;
  if (threadIdx.x == 0) carry = 0;
  __syncthreads();
  for (int base = 0; base < n; base += 1024){
    int i = base + threadIdx.x;
    int v = (i < n) ? cnt[i] : 0;
    sdata[threadIdx.x] = v;
    __syncthreads();
    #pragma unroll
    for (int s = 1; s < 1024; s <<= 1){
      int t = 0;
      if ((int)threadIdx.x >= s) t = sdata[threadIdx.x - s];
      __syncthreads();
      sdata[threadIdx.x] += t;
      __syncthreads();
    }
    int excl = sdata[threadIdx.x] - v + carry;
    if (i < n){ off[i] = excl; cursor[i] = excl; }
    __syncthreads();
    if (threadIdx.x == 1023) carry += sdata[1023];
    __syncthreads();
  }
  if (threadIdx.x == 0) off[n] = carry;
}

// bucket edges by destination; store src and final edge weight dinv[r]*w*dinv[c]
__global__ __launch_bounds__(256) void scatter_k(const int* __restrict__ row, const int* __restrict__ col,
    const float* __restrict__ ew, const float* __restrict__ dinv,
    int* __restrict__ cursor, int* __restrict__ csr_src, float* __restrict__ csr_w, int E){
  int e = blockIdx.x*256 + threadIdx.x;
  if (e < E){
    int r = row[e], c = col[e];
    int slot = atomicAdd(&cursor[c], 1);
    csr_src[slot] = r;
    csr_w[slot]  = dinv[r] * ew[e] * dinv[c];
  }
}

// CSR gather aggregation: agg[n] = dinv[n]^2*h[n] + sum_j w[j]*h[src[j]], 2 nodes/block
__global__ __launch_bounds__(256) void agg_gather_k(const float* __restrict__ h,
    const int* __restrict__ off, const int* __restrict__ src, const float* __restrict__ w,
    const float* __restrict__ dinv, float* __restrict__ agg, int Nn){
  int ln = threadIdx.x >> 7;
  int k  = threadIdx.x & 127;
  int n  = blockIdx.x*2 + ln;
  if (n >= Nn) return;
  float d = dinv[n];
  float acc = d*d*h[(size_t)n*128 + k];
  int s = off[n], e = off[n+1];
  int j = s;
  for (; j + 1 < e; j += 2){
    int r0 = src[j], r1 = src[j+1];
    float w0 = w[j], w1 = w[j+1];
    acc += w0 * h[(size_t)r0*128 + k];
    acc += w1 * h[(size_t)r1*128 + k];
  }
  if (j < e) acc += w[j] * h[(size_t)src[j]*128 + k];
  agg[(size_t)n*128 + k] = acc;
}

extern "C" void kernel_launch(void* const* d_in, const int* in_sizes, int n_in,
                              void* d_out, int out_size, void* d_ws, size_t ws_size,
                              hipStream_t stream){
  const float* x      = (const float*)d_in[0];
  const int*   ei     = (const int*)  d_in[1];
  const float* w1     = (const float*)d_in[2];
  const float* b1     = (const float*)d_in[3];
  const float* w2     = (const float*)d_in[4];
  const float* b2     = (const float*)d_in[5];
  const float* w3     = (const float*)d_in[6];
  const float* b3     = (const float*)d_in[7];
  const float* pars   = (const float*)d_in[8];
  const float* lin0w  = (const float*)d_in[9];
  const float* lin0b  = (const float*)d_in[10];
  const float* lin1w  = (const float*)d_in[11];
  const float* lin1b  = (const float*)d_in[12];
  const float* cw1    = (const float*)d_in[13];
  float* out          = (float*)d_out;

  float* ws = (float*)d_ws;
  // workspace layout (element offsets)
  float* logits  = ws + 3200000;
  float* logitsP = ws + 6400000;
  float* ew      = ws + 9600000;           //   800,000
  float* deg     = ws + 10400000;          //    50,000 (becomes dinv)
  float* scal    = ws + 10450048;          //        16
  float* bufA    = ws + 10450176;          // 6,400,000
  float* bufB    = ws + 16850176;          // 6,400,000
  float* bufC    = ws + 23250176;          // 6,400,000
  // CSR overlay on the (now unused) first region:
  int*   cnt     = (int*)(ws + 0);         //    50,000
  int*   off     = (int*)(ws + 50048);     //    50,001
  int*   cursor  = (int*)(ws + 100096);    //    50,000
  int*   csr_src = (int*)(ws + 150144);    //   800,000
  float* csr_w   = ws + 950144;            //   800,000
  // bf16 transposed weights overlay on bufC (consumed before bufC is written):
  short* w1t     = (short*)bufC;           //  65,536 shorts
  short* w2t     = w1t + 65536;            //  32,768
  short* w3t     = w2t + 32768;            //   4,096
  short* Pt      = w3t + 4096;             //   4,096

  const int Mn = NN, E = NE;
  const int* erow = ei;
  const int* ecol = ei + E;
  const float beta0 = 0.69314718055994530942f;  // ln(2)
  const float beta1 = 0.40546510810816438198f;  // ln(1.5)

  // 1) init deg=1, scalars=0; weight prep
  init_k<<<(Mn+255)/256, 256, 0, stream>>>(deg, scal, Mn);
  prep_k<<<(106496+255)/256, 256, 0, stream>>>(w1, w2, w3, pars, w1t, w2t, w3t, Pt);
  // 2) fused bf16-MFMA MLP chain -> logits, logitsP
  mlp_mfma_k<<<(Mn+31)/32, 256, 0, stream>>>(x, w1t, b1, w2t, b2, w3t, b3, Pt,
                                             logits, logitsP, Mn);
  zero_cnt_k<<<(Mn+255)/256, 256, 0, stream>>>(cnt, Mn);
  // 3) ew + stats
  ew_k<<<2048, 256, 0, stream>>>(logits, logitsP, erow, ecol, ew, scal, E);
  finalize_k<<<1, 1, 0, stream>>>(scal, E);
  // 4) normalize ew, degree (float) + count (int) accumulation; dinv
  ewnorm_k<<<(E+255)/256, 256, 0, stream>>>(ew, ecol, deg, cnt, scal, E);
  dinv_k<<<(Mn+255)/256, 256, 0, stream>>>(deg, Mn);
  // 5) CSR build: scan + bucket scatter (stores final edge weights)
  scan_k<<<1, 1024, 0, stream>>>(cnt, off, cursor, Mn);
  scatter_k<<<(E+255)/256, 256, 0, stream>>>(erow, ecol, ew, deg, cursor, csr_src, csr_w, E);
  // 6) x0 = relu(x@lin0w + lin0b) -> bufA
  dim3 g128(2, (Mn+63)/64);
  gemm_k<true,true,false><<<g128, 256, 0, stream>>>(x, lin0w, lin0b, nullptr, bufA, Mn, 128, 128, 0.f);
  // 7) layer 0: gather agg(bufB) from bufA; hnext(bufC)
  agg_gather_k<<<(Mn+1)/2, 256, 0, stream>>>(bufA, off, csr_src, csr_w, deg, bufB, Mn);
  gemm_k<false,true,true><<<g128, 256, 0, stream>>>(bufB, cw1, nullptr, bufB, bufC, Mn, 128, 128, beta0);
  // 8) layer 1: gather agg(bufA) from bufC; hnext(bufB)
  agg_gather_k<<<(Mn+1)/2, 256, 0, stream>>>(bufC, off, csr_src, csr_w, deg, bufA, Mn);
  gemm_k<false,true,true><<<g128, 256, 0, stream>>>(bufA, cw1 + 128*128, nullptr, bufA, bufB, Mn, 128, 128, beta1);
  // 9) out = bufB @ lin1w + lin1b
  gemm_k<true,false,false><<<dim3(1,(Mn+63)/64), 256, 0, stream>>>(bufB, lin1w, lin1b, nullptr, out, Mn, 64, 128, 0.f);
}

// Round 4
// 678.140 us; speedup vs baseline: 2.0059x; 1.2033x over previous
//
#include <hip/hip_runtime.h>
#include <hip/hip_bf16.h>
#include <math.h>

#define NN 50000
#define NE 800000

typedef __attribute__((ext_vector_type(8))) short bf16x8;
typedef __attribute__((ext_vector_type(4))) float f32x4;

__device__ __forceinline__ short f2bf(float f){
  unsigned u = __float_as_uint(f);
  unsigned r = (u + 0x7fffu + ((u >> 16) & 1u)) >> 16;
  return (short)r;
}
__device__ __forceinline__ float bf2f(short s){
  return __uint_as_float(((unsigned)(unsigned short)s) << 16);
}

// ---------------- init: deg=1 (self loop), zero stat scalars ----------------
__global__ __launch_bounds__(256) void init_k(float* __restrict__ deg, float* __restrict__ scal, int n){
  int i = blockIdx.x*256 + threadIdx.x;
  if (i < n) deg[i] = 1.0f;
  if (blockIdx.x == 0 && threadIdx.x < 16) scal[threadIdx.x] = 0.0f;
}

__global__ __launch_bounds__(256) void zero_cnt_k(int* __restrict__ cnt, int n){
  int i = blockIdx.x*256 + threadIdx.x;
  if (i < n) cnt[i] = 0;
}

// ---------------- weight prep: transpose + bf16 convert ----------------
__global__ __launch_bounds__(256) void prep_k(const float* __restrict__ w1,
    const float* __restrict__ w2, const float* __restrict__ w3, const float* __restrict__ pars,
    short* __restrict__ w1t, short* __restrict__ w2t, short* __restrict__ w3t, short* __restrict__ Pt){
  int idx = blockIdx.x*256 + threadIdx.x;
  if (idx < 65536){
    int n = idx >> 7, k = idx & 127;
    w1t[idx] = f2bf(w1[k*512 + n]);
  } else if (idx < 98304){
    int i = idx - 65536; int n = i >> 9, k = i & 511;
    w2t[i] = f2bf(w2[k*64 + n]);
  } else if (idx < 102400){
    int i = idx - 98304; int n = i >> 6, k = i & 63;
    w3t[i] = f2bf(w3[k*64 + n]);
  } else if (idx < 106496){
    int i = idx - 102400; int n = i >> 6, k = i & 63;
    Pt[i] = f2bf(fmaxf(2.f*pars[k*64 + n], 0.f));
  }
}

// ---------------- fused bf16-MFMA MLP chain -> bf16 logits / logitsP ----------------
__global__ __launch_bounds__(256) void mlp_mfma_k(
    const float* __restrict__ x,
    const short* __restrict__ w1t, const float* __restrict__ b1,
    const short* __restrict__ w2t, const float* __restrict__ b2,
    const short* __restrict__ w3t, const float* __restrict__ b3,
    const short* __restrict__ Pt,
    short* __restrict__ lgb, short* __restrict__ lgpb, int M)
{
  __shared__ short xs [32][136];
  __shared__ short h1s[32][520];
  __shared__ short h2s[32][72];   // phase2 out; reused as lgpb staging in phase 4
  __shared__ short lgs[32][72];
  const int t = threadIdx.x;
  const int wave = t >> 6, lane = t & 63;
  const int quad = lane >> 4, l16 = lane & 15;
  const int m0 = blockIdx.x * 32;

  // ---- stage x -> xs (bf16) ----
  for (int task = t; task < 512; task += 256){
    int row = task >> 4, c0 = (task & 15) * 8;
    float4 v0 = make_float4(0,0,0,0), v1 = v0;
    if (m0 + row < M){
      v0 = *(const float4*)(x + (size_t)(m0+row)*128 + c0);
      v1 = *(const float4*)(x + (size_t)(m0+row)*128 + c0 + 4);
    }
    bf16x8 s;
    s[0]=f2bf(v0.x); s[1]=f2bf(v0.y); s[2]=f2bf(v0.z); s[3]=f2bf(v0.w);
    s[4]=f2bf(v1.x); s[5]=f2bf(v1.y); s[6]=f2bf(v1.z); s[7]=f2bf(v1.w);
    *(bf16x8*)&xs[row][c0] = s;
  }
  __syncthreads();

  // ---- Phase 1: h1 = relu(x @ w1 + b1) ----
  {
    f32x4 acc[2][8];
    #pragma unroll
    for (int mt=0;mt<2;mt++)
      #pragma unroll
      for (int nt=0;nt<8;nt++) acc[mt][nt] = (f32x4){0.f,0.f,0.f,0.f};
    for (int k0 = 0; k0 < 128; k0 += 32){
      bf16x8 a0 = *(const bf16x8*)&xs[l16     ][k0 + quad*8];
      bf16x8 a1 = *(const bf16x8*)&xs[16 + l16][k0 + quad*8];
      #pragma unroll
      for (int nt = 0; nt < 8; nt++){
        int n = wave*128 + nt*16 + l16;
        bf16x8 b = *(const bf16x8*)(w1t + (size_t)n*128 + k0 + quad*8);
        acc[0][nt] = __builtin_amdgcn_mfma_f32_16x16x32_bf16(a0, b, acc[0][nt], 0,0,0);
        acc[1][nt] = __builtin_amdgcn_mfma_f32_16x16x32_bf16(a1, b, acc[1][nt], 0,0,0);
      }
    }
    #pragma unroll
    for (int nt = 0; nt < 8; nt++){
      int n = wave*128 + nt*16 + l16;
      float bb = b1[n];
      #pragma unroll
      for (int mt = 0; mt < 2; mt++){
        #pragma unroll
        for (int r = 0; r < 4; r++){
          int row = mt*16 + quad*4 + r;
          h1s[row][n] = f2bf(fmaxf(acc[mt][nt][r] + bb, 0.f));
        }
      }
    }
  }
  __syncthreads();

  // ---- Phase 2: h2 = relu(h1 @ w2 + b2) ----
  {
    f32x4 acc[2];
    acc[0] = (f32x4){0.f,0.f,0.f,0.f}; acc[1] = acc[0];
    const int n = wave*16 + l16;
    for (int k0 = 0; k0 < 512; k0 += 32){
      bf16x8 b  = *(const bf16x8*)(w2t + (size_t)n*512 + k0 + quad*8);
      bf16x8 a0 = *(const bf16x8*)&h1s[l16     ][k0 + quad*8];
      bf16x8 a1 = *(const bf16x8*)&h1s[16 + l16][k0 + quad*8];
      acc[0] = __builtin_amdgcn_mfma_f32_16x16x32_bf16(a0, b, acc[0], 0,0,0);
      acc[1] = __builtin_amdgcn_mfma_f32_16x16x32_bf16(a1, b, acc[1], 0,0,0);
    }
    float bb = b2[n];
    #pragma unroll
    for (int mt = 0; mt < 2; mt++)
      #pragma unroll
      for (int r = 0; r < 4; r++)
        h2s[mt*16 + quad*4 + r][n] = f2bf(fmaxf(acc[mt][r] + bb, 0.f));
  }
  __syncthreads();

  // ---- Phase 3: logits = h2 @ w3 + b3 -> lgs (bf16 LDS) ----
  {
    f32x4 acc[2];
    acc[0] = (f32x4){0.f,0.f,0.f,0.f}; acc[1] = acc[0];
    const int n = wave*16 + l16;
    for (int k0 = 0; k0 < 64; k0 += 32){
      bf16x8 b  = *(const bf16x8*)(w3t + (size_t)n*64 + k0 + quad*8);
      bf16x8 a0 = *(const bf16x8*)&h2s[l16     ][k0 + quad*8];
      bf16x8 a1 = *(const bf16x8*)&h2s[16 + l16][k0 + quad*8];
      acc[0] = __builtin_amdgcn_mfma_f32_16x16x32_bf16(a0, b, acc[0], 0,0,0);
      acc[1] = __builtin_amdgcn_mfma_f32_16x16x32_bf16(a1, b, acc[1], 0,0,0);
    }
    float bb = b3[n];
    #pragma unroll
    for (int mt = 0; mt < 2; mt++)
      #pragma unroll
      for (int r = 0; r < 4; r++)
        lgs[mt*16 + quad*4 + r][n] = f2bf(acc[mt][r] + bb);
  }
  __syncthreads();

  // ---- Phase 4: logitsP = logits @ relu(2P) -> h2s (staging) ----
  {
    f32x4 acc[2];
    acc[0] = (f32x4){0.f,0.f,0.f,0.f}; acc[1] = acc[0];
    const int n = wave*16 + l16;
    for (int k0 = 0; k0 < 64; k0 += 32){
      bf16x8 b  = *(const bf16x8*)(Pt + (size_t)n*64 + k0 + quad*8);
      bf16x8 a0 = *(const bf16x8*)&lgs[l16     ][k0 + quad*8];
      bf16x8 a1 = *(const bf16x8*)&lgs[16 + l16][k0 + quad*8];
      acc[0] = __builtin_amdgcn_mfma_f32_16x16x32_bf16(a0, b, acc[0], 0,0,0);
      acc[1] = __builtin_amdgcn_mfma_f32_16x16x32_bf16(a1, b, acc[1], 0,0,0);
    }
    #pragma unroll
    for (int mt = 0; mt < 2; mt++)
      #pragma unroll
      for (int r = 0; r < 4; r++)
        h2s[mt*16 + quad*4 + r][n] = f2bf(acc[mt][r]);
  }
  __syncthreads();

  // ---- cooperative vectorized store of lgs -> lgb and h2s -> lgpb ----
  {
    int row = t >> 3, c0 = (t & 7) * 8;
    int gm = m0 + row;
    if (gm < M){
      *(bf16x8*)(lgb  + (size_t)gm*64 + c0) = *(const bf16x8*)&lgs[row][c0];
      *(bf16x8*)(lgpb + (size_t)gm*64 + c0) = *(const bf16x8*)&h2s[row][c0];
    }
  }
}

// ---------------- generic tiled fp32 GEMM, 64x64 tile ----------------
template<bool BIAS, bool RELU, bool RESID, bool BF16OUT>
__global__ __launch_bounds__(256) void gemm_k(const float* __restrict__ A, const float* __restrict__ B,
    const float* __restrict__ bias, const float* __restrict__ extra,
    float* __restrict__ C, short* __restrict__ Cb,
    int M, int N, int K, float beta){
  __shared__ float As[16][68];
  __shared__ float Bs[16][68];
  const int n0 = blockIdx.x*64, m0 = blockIdx.y*64;
  const int t = threadIdx.x;
  const int tx = t & 15, ty = t >> 4;
  float acc[4][4] = {{0.f}};
  for (int k0 = 0; k0 < K; k0 += 16){
    {
      int row = t >> 2, kq = t & 3;
      int gm = m0 + row;
      float4 a4 = make_float4(0.f,0.f,0.f,0.f);
      if (gm < M) a4 = *(const float4*)(A + (size_t)gm*K + k0 + kq*4);
      As[kq*4+0][row] = a4.x; As[kq*4+1][row] = a4.y;
      As[kq*4+2][row] = a4.z; As[kq*4+3][row] = a4.w;
    }
    {
      int kk = t >> 4, nq = t & 15;
      float4 b4 = *(const float4*)(B + (size_t)(k0+kk)*N + n0 + nq*4);
      *(float4*)&Bs[kk][nq*4] = b4;
    }
    __syncthreads();
    #pragma unroll
    for (int kk=0; kk<16; kk++){
      float4 a4 = *(const float4*)&As[kk][ty*4];
      float4 b4 = *(const float4*)&Bs[kk][tx*4];
      acc[0][0] += a4.x*b4.x; acc[0][1] += a4.x*b4.y; acc[0][2] += a4.x*b4.z; acc[0][3] += a4.x*b4.w;
      acc[1][0] += a4.y*b4.x; acc[1][1] += a4.y*b4.y; acc[1][2] += a4.y*b4.z; acc[1][3] += a4.y*b4.w;
      acc[2][0] += a4.z*b4.x; acc[2][1] += a4.z*b4.y; acc[2][2] += a4.z*b4.z; acc[2][3] += a4.z*b4.w;
      acc[3][0] += a4.w*b4.x; acc[3][1] += a4.w*b4.y; acc[3][2] += a4.w*b4.z; acc[3][3] += a4.w*b4.w;
    }
    __syncthreads();
  }
  const int nc = n0 + tx*4;
  float4 bb = make_float4(0.f,0.f,0.f,0.f);
  if (BIAS) bb = *(const float4*)(bias + nc);
  #pragma unroll
  for (int i=0;i<4;i++){
    int gm = m0 + ty*4 + i;
    if (gm >= M) continue;
    float4 v = make_float4(acc[i][0], acc[i][1], acc[i][2], acc[i][3]);
    if (RESID){
      float4 ex = *(const float4*)(extra + (size_t)gm*N + nc);
      float ob = 1.f - beta;
      v.x = beta*v.x + ob*ex.x; v.y = beta*v.y + ob*ex.y;
      v.z = beta*v.z + ob*ex.z; v.w = beta*v.w + ob*ex.w;
    }
    if (BIAS){ v.x += bb.x; v.y += bb.y; v.z += bb.z; v.w += bb.w; }
    if (RELU){
      v.x = fmaxf(v.x,0.f); v.y = fmaxf(v.y,0.f);
      v.z = fmaxf(v.z,0.f); v.w = fmaxf(v.w,0.f);
    }
    if (BF16OUT){
      short4 sv;
      sv.x = f2bf(v.x); sv.y = f2bf(v.y); sv.z = f2bf(v.z); sv.w = f2bf(v.w);
      *(short4*)(Cb + (size_t)gm*N + nc) = sv;
    } else {
      *(float4*)(C + (size_t)gm*N + nc) = v;
    }
  }
}

// ---------------- ew: 16 lanes/edge, bf16 gathers + stats ----------------
__global__ __launch_bounds__(256) void ew_k(const short* __restrict__ lgb, const short* __restrict__ lgpb,
    const int* __restrict__ row, const int* __restrict__ col,
    float* __restrict__ ew, float* __restrict__ scal, int E){
  const int t = threadIdx.x;
  const int lane = t & 63, wid = t >> 6;
  const int g = lane >> 4, q = lane & 15;
  const int gw = blockIdx.x*4 + wid;
  const int stride = gridDim.x*4*4;
  float s = 0.f, ss = 0.f;
  for (int e = gw*4 + g; e < E; e += stride){
    int r = row[e], c = col[e];
    short4 a = *(const short4*)(lgb  + (size_t)r*64 + q*4);
    short4 b = *(const short4*)(lgpb + (size_t)c*64 + q*4);
    float v = bf2f(a.x)*bf2f(b.x) + bf2f(a.y)*bf2f(b.y)
            + bf2f(a.z)*bf2f(b.z) + bf2f(a.w)*bf2f(b.w);
    v += __shfl_xor(v, 1); v += __shfl_xor(v, 2);
    v += __shfl_xor(v, 4); v += __shfl_xor(v, 8);
    if (q == 0){ ew[e] = v; s += v; ss += v*v; }
  }
  s  += __shfl_xor(s, 16);  s  += __shfl_xor(s, 32);
  ss += __shfl_xor(ss, 16); ss += __shfl_xor(ss, 32);
  __shared__ float ls[4], lss[4];
  if (lane == 0){ ls[wid] = s; lss[wid] = ss; }
  __syncthreads();
  if (t == 0){
    atomicAdd(&scal[0], ls[0]+ls[1]+ls[2]+ls[3]);
    atomicAdd(&scal[1], lss[0]+lss[1]+lss[2]+lss[3]);
  }
}

__global__ void finalize_k(float* scal, int E){
  double sum = (double)scal[0], sumsq = (double)scal[1];
  double mean = sum / (double)E;
  double var  = (sumsq - sum*sum/(double)E) / (double)(E-1);
  scal[2] = (float)mean;
  scal[3] = (float)sqrt(1e-4 / var);
}

// normalize ew, accumulate float degree at col, int count at col (for CSR)
__global__ __launch_bounds__(256) void ewnorm_k(float* __restrict__ ew, const int* __restrict__ col,
    float* __restrict__ deg, int* __restrict__ cnt, const float* __restrict__ scal, int E){
  int e = blockIdx.x*256 + threadIdx.x;
  if (e < E){
    float w = (ew[e] - scal[2]) * scal[3] + 1.0f;
    ew[e] = w;
    int c = col[e];
    atomicAdd(&deg[c], w);
    atomicAdd(&cnt[c], 1);
  }
}

__global__ __launch_bounds__(256) void dinv_k(float* __restrict__ deg, int n){
  int i = blockIdx.x*256 + threadIdx.x;
  if (i < n){ float d = deg[i]; deg[i] = (d > 0.f) ? rsqrtf(d) : 0.f; }
}

// single-block exclusive scan over cnt -> off[0..n], cursor copy
__global__ __launch_bounds__(1024) void scan_k(const int* __restrict__ cnt, int* __restrict__ off,
    int* __restrict__ cursor, int n){
  __shared__ int sdata[1024];
  __shared__ int carry;
  if (threadIdx.x == 0) carry = 0;
  __syncthreads();
  for (int base = 0; base < n; base += 1024){
    int i = base + threadIdx.x;
    int v = (i < n) ? cnt[i] : 0;
    sdata[threadIdx.x] = v;
    __syncthreads();
    #pragma unroll
    for (int s = 1; s < 1024; s <<= 1){
      int t = 0;
      if ((int)threadIdx.x >= s) t = sdata[threadIdx.x - s];
      __syncthreads();
      sdata[threadIdx.x] += t;
      __syncthreads();
    }
    int excl = sdata[threadIdx.x] - v + carry;
    if (i < n){ off[i] = excl; cursor[i] = excl; }
    __syncthreads();
    if (threadIdx.x == 1023) carry += sdata[1023];
    __syncthreads();
  }
  if (threadIdx.x == 0) off[n] = carry;
}

// bucket edges by destination; store src and final edge weight dinv[r]*w*dinv[c]
__global__ __launch_bounds__(256) void scatter_k(const int* __restrict__ row, const int* __restrict__ col,
    const float* __restrict__ ew, const float* __restrict__ dinv,
    int* __restrict__ cursor, int* __restrict__ csr_src, float* __restrict__ csr_w, int E){
  int e = blockIdx.x*256 + threadIdx.x;
  if (e < E){
    int r = row[e], c = col[e];
    int slot = atomicAdd(&cursor[c], 1);
    csr_src[slot] = r;
    csr_w[slot]  = dinv[r] * ew[e] * dinv[c];
  }
}

// CSR gather aggregation from bf16 h: wave per node, 2 channels/lane
__global__ __launch_bounds__(256) void agg_gather_k(const short* __restrict__ hb,
    const int* __restrict__ off, const int* __restrict__ src, const float* __restrict__ w,
    const float* __restrict__ dinv, float* __restrict__ agg, int Nn){
  int n = blockIdx.x*4 + (threadIdx.x >> 6);
  int lane = threadIdx.x & 63;
  if (n >= Nn) return;
  float d = dinv[n];
  short2 hv = *(const short2*)(hb + (size_t)n*128 + lane*2);
  float acc0 = d*d*bf2f(hv.x), acc1 = d*d*bf2f(hv.y);
  int s = off[n], e = off[n+1];
  int j = s;
  for (; j + 1 < e; j += 2){
    int r0 = src[j], r1 = src[j+1];
    float w0 = w[j], w1 = w[j+1];
    short2 h0 = *(const short2*)(hb + (size_t)r0*128 + lane*2);
    short2 h1 = *(const short2*)(hb + (size_t)r1*128 + lane*2);
    acc0 += w0*bf2f(h0.x) + w1*bf2f(h1.x);
    acc1 += w0*bf2f(h0.y) + w1*bf2f(h1.y);
  }
  if (j < e){
    short2 h0 = *(const short2*)(hb + (size_t)src[j]*128 + lane*2);
    float w0 = w[j];
    acc0 += w0*bf2f(h0.x); acc1 += w0*bf2f(h0.y);
  }
  *(float2*)(agg + (size_t)n*128 + lane*2) = make_float2(acc0, acc1);
}

extern "C" void kernel_launch(void* const* d_in, const int* in_sizes, int n_in,
                              void* d_out, int out_size, void* d_ws, size_t ws_size,
                              hipStream_t stream){
  const float* x      = (const float*)d_in[0];
  const int*   ei     = (const int*)  d_in[1];
  const float* w1     = (const float*)d_in[2];
  const float* b1     = (const float*)d_in[3];
  const float* w2     = (const float*)d_in[4];
  const float* b2     = (const float*)d_in[5];
  const float* w3     = (const float*)d_in[6];
  const float* b3     = (const float*)d_in[7];
  const float* pars   = (const float*)d_in[8];
  const float* lin0w  = (const float*)d_in[9];
  const float* lin0b  = (const float*)d_in[10];
  const float* lin1w  = (const float*)d_in[11];
  const float* lin1b  = (const float*)d_in[12];
  const float* cw1    = (const float*)d_in[13];
  float* out          = (float*)d_out;

  float* ws = (float*)d_ws;
  // workspace layout (float-element offsets)
  int*   cnt     = (int*)(ws + 0);            //    50,000
  int*   off     = (int*)(ws + 50048);        //    50,001
  int*   cursor  = (int*)(ws + 100096);       //    50,000
  int*   csr_src = (int*)(ws + 150144);       //   800,000
  float* csr_w   = ws + 950144;               //   800,000 (ends 1,750,144)
  short* lgb     = (short*)(ws + 1800000);    // 3.2M shorts (1.6M floats)
  short* lgpb    = (short*)(ws + 3400000);    // 3.2M shorts
  float* ew      = ws + 5000000;              //   800,000
  float* deg     = ws + 5800000;              //    50,000
  float* scal    = ws + 5850048;              //        16
  short* bufAb   = (short*)(ws + 5900000);    // 6.4M shorts (3.2M floats)
  short* bufCb   = (short*)(ws + 9100000);    // 6.4M shorts
  float* bufAgg  = ws + 12300000;             // 6,400,000
  float* bufB    = ws + 18700000;             // 6,400,000 (ends 25,100,000 ~ 100 MB)
  // bf16 transposed MLP weights overlay on bufB (consumed before bufB written):
  short* w1t     = (short*)bufB;              //  65,536 shorts
  short* w2t     = w1t + 65536;               //  32,768
  short* w3t     = w2t + 32768;               //   4,096
  short* Pt      = w3t + 4096;                //   4,096

  const int Mn = NN, E = NE;
  const int* erow = ei;
  const int* ecol = ei + E;
  const float beta0 = 0.69314718055994530942f;  // ln(2)
  const float beta1 = 0.40546510810816438198f;  // ln(1.5)

  // 1) init + weight prep
  init_k<<<(Mn+255)/256, 256, 0, stream>>>(deg, scal, Mn);
  prep_k<<<(106496+255)/256, 256, 0, stream>>>(w1, w2, w3, pars, w1t, w2t, w3t, Pt);
  // 2) fused bf16-MFMA MLP chain -> lgb, lgpb (bf16)
  mlp_mfma_k<<<(Mn+31)/32, 256, 0, stream>>>(x, w1t, b1, w2t, b2, w3t, b3, Pt,
                                             lgb, lgpb, Mn);
  zero_cnt_k<<<(Mn+255)/256, 256, 0, stream>>>(cnt, Mn);
  // 3) ew + stats (bf16 gathers, 16 lanes/edge)
  ew_k<<<2048, 256, 0, stream>>>(lgb, lgpb, erow, ecol, ew, scal, E);
  finalize_k<<<1, 1, 0, stream>>>(scal, E);
  // 4) normalize ew, degree + count accumulation; dinv
  ewnorm_k<<<(E+255)/256, 256, 0, stream>>>(ew, ecol, deg, cnt, scal, E);
  dinv_k<<<(Mn+255)/256, 256, 0, stream>>>(deg, Mn);
  // 5) CSR build
  scan_k<<<1, 1024, 0, stream>>>(cnt, off, cursor, Mn);
  scatter_k<<<(E+255)/256, 256, 0, stream>>>(erow, ecol, ew, deg, cursor, csr_src, csr_w, E);
  // 6) x0 = relu(x@lin0w + lin0b) -> bufAb (bf16 only; fp32 form never read)
  dim3 g128(2, (Mn+63)/64);
  gemm_k<true,true,false,true><<<g128, 256, 0, stream>>>(x, lin0w, lin0b, nullptr, nullptr, bufAb, Mn, 128, 128, 0.f);
  // 7) layer 0: gather agg from bufAb; hnext -> bufCb (bf16 only)
  agg_gather_k<<<(Mn+3)/4, 256, 0, stream>>>(bufAb, off, csr_src, csr_w, deg, bufAgg, Mn);
  gemm_k<false,true,true,true><<<g128, 256, 0, stream>>>(bufAgg, cw1, nullptr, bufAgg, nullptr, bufCb, Mn, 128, 128, beta0);
  // 8) layer 1: gather agg from bufCb; hnext -> bufB (fp32, feeds final GEMM)
  agg_gather_k<<<(Mn+3)/4, 256, 0, stream>>>(bufCb, off, csr_src, csr_w, deg, bufAgg, Mn);
  gemm_k<false,true,true,false><<<g128, 256, 0, stream>>>(bufAgg, cw1 + 128*128, nullptr, bufAgg, bufB, nullptr, Mn, 128, 128, beta1);
  // 9) out = bufB @ lin1w + lin1b
  gemm_k<true,false,false,false><<<dim3(1,(Mn+63)/64), 256, 0, stream>>>(bufB, lin1w, lin1b, nullptr, out, nullptr, Mn, 64, 128, 0.f);
}

// Round 5
// 584.804 us; speedup vs baseline: 2.3261x; 1.1596x over previous
//
#include <hip/hip_runtime.h>
#include <hip/hip_bf16.h>
#include <math.h>

#define NN 50000
#define NE 800000

typedef __attribute__((ext_vector_type(8))) short bf16x8;
typedef __attribute__((ext_vector_type(4))) float f32x4;

__device__ __forceinline__ short f2bf(float f){
  unsigned u = __float_as_uint(f);
  unsigned r = (u + 0x7fffu + ((u >> 16) & 1u)) >> 16;
  return (short)r;
}
__device__ __forceinline__ float bf2f(short s){
  return __uint_as_float(((unsigned)(unsigned short)s) << 16);
}

// ---------------- init: deg=1 (self loop), zero stat scalars ----------------
__global__ __launch_bounds__(256) void init_k(float* __restrict__ deg, float* __restrict__ scal, int n){
  int i = blockIdx.x*256 + threadIdx.x;
  if (i < n) deg[i] = 1.0f;
  if (blockIdx.x == 0 && threadIdx.x < 16) scal[threadIdx.x] = 0.0f;
}

__global__ __launch_bounds__(256) void zero_cnt_k(int* __restrict__ cnt, int n){
  int i = blockIdx.x*256 + threadIdx.x;
  if (i < n) cnt[i] = 0;
}

// ---------------- weight prep: transpose + bf16 convert ----------------
__global__ __launch_bounds__(256) void prep_k(const float* __restrict__ w1,
    const float* __restrict__ w2, const float* __restrict__ w3, const float* __restrict__ pars,
    short* __restrict__ w1t, short* __restrict__ w2t, short* __restrict__ w3t, short* __restrict__ Pt){
  int idx = blockIdx.x*256 + threadIdx.x;
  if (idx < 65536){
    int n = idx >> 7, k = idx & 127;
    w1t[idx] = f2bf(w1[k*512 + n]);
  } else if (idx < 98304){
    int i = idx - 65536; int n = i >> 9, k = i & 511;
    w2t[i] = f2bf(w2[k*64 + n]);
  } else if (idx < 102400){
    int i = idx - 98304; int n = i >> 6, k = i & 63;
    w3t[i] = f2bf(w3[k*64 + n]);
  } else if (idx < 106496){
    int i = idx - 102400; int n = i >> 6, k = i & 63;
    Pt[i] = f2bf(fmaxf(2.f*pars[k*64 + n], 0.f));
  }
}

// ---------------- fused bf16-MFMA MLP chain -> bf16 logits / logitsP ----------------
__global__ __launch_bounds__(256) void mlp_mfma_k(
    const float* __restrict__ x,
    const short* __restrict__ w1t, const float* __restrict__ b1,
    const short* __restrict__ w2t, const float* __restrict__ b2,
    const short* __restrict__ w3t, const float* __restrict__ b3,
    const short* __restrict__ Pt,
    short* __restrict__ lgb, short* __restrict__ lgpb, int M)
{
  __shared__ short xs [32][136];
  __shared__ short h1s[32][520];
  __shared__ short h2s[32][72];   // phase2 out; reused as lgpb staging in phase 4
  __shared__ short lgs[32][72];
  const int t = threadIdx.x;
  const int wave = t >> 6, lane = t & 63;
  const int quad = lane >> 4, l16 = lane & 15;
  const int m0 = blockIdx.x * 32;

  for (int task = t; task < 512; task += 256){
    int row = task >> 4, c0 = (task & 15) * 8;
    float4 v0 = make_float4(0,0,0,0), v1 = v0;
    if (m0 + row < M){
      v0 = *(const float4*)(x + (size_t)(m0+row)*128 + c0);
      v1 = *(const float4*)(x + (size_t)(m0+row)*128 + c0 + 4);
    }
    bf16x8 s;
    s[0]=f2bf(v0.x); s[1]=f2bf(v0.y); s[2]=f2bf(v0.z); s[3]=f2bf(v0.w);
    s[4]=f2bf(v1.x); s[5]=f2bf(v1.y); s[6]=f2bf(v1.z); s[7]=f2bf(v1.w);
    *(bf16x8*)&xs[row][c0] = s;
  }
  __syncthreads();

  // ---- Phase 1: h1 = relu(x @ w1 + b1) ----
  {
    f32x4 acc[2][8];
    #pragma unroll
    for (int mt=0;mt<2;mt++)
      #pragma unroll
      for (int nt=0;nt<8;nt++) acc[mt][nt] = (f32x4){0.f,0.f,0.f,0.f};
    for (int k0 = 0; k0 < 128; k0 += 32){
      bf16x8 a0 = *(const bf16x8*)&xs[l16     ][k0 + quad*8];
      bf16x8 a1 = *(const bf16x8*)&xs[16 + l16][k0 + quad*8];
      #pragma unroll
      for (int nt = 0; nt < 8; nt++){
        int n = wave*128 + nt*16 + l16;
        bf16x8 b = *(const bf16x8*)(w1t + (size_t)n*128 + k0 + quad*8);
        acc[0][nt] = __builtin_amdgcn_mfma_f32_16x16x32_bf16(a0, b, acc[0][nt], 0,0,0);
        acc[1][nt] = __builtin_amdgcn_mfma_f32_16x16x32_bf16(a1, b, acc[1][nt], 0,0,0);
      }
    }
    #pragma unroll
    for (int nt = 0; nt < 8; nt++){
      int n = wave*128 + nt*16 + l16;
      float bb = b1[n];
      #pragma unroll
      for (int mt = 0; mt < 2; mt++){
        #pragma unroll
        for (int r = 0; r < 4; r++){
          int row = mt*16 + quad*4 + r;
          h1s[row][n] = f2bf(fmaxf(acc[mt][nt][r] + bb, 0.f));
        }
      }
    }
  }
  __syncthreads();

  // ---- Phase 2: h2 = relu(h1 @ w2 + b2) ----
  {
    f32x4 acc[2];
    acc[0] = (f32x4){0.f,0.f,0.f,0.f}; acc[1] = acc[0];
    const int n = wave*16 + l16;
    for (int k0 = 0; k0 < 512; k0 += 32){
      bf16x8 b  = *(const bf16x8*)(w2t + (size_t)n*512 + k0 + quad*8);
      bf16x8 a0 = *(const bf16x8*)&h1s[l16     ][k0 + quad*8];
      bf16x8 a1 = *(const bf16x8*)&h1s[16 + l16][k0 + quad*8];
      acc[0] = __builtin_amdgcn_mfma_f32_16x16x32_bf16(a0, b, acc[0], 0,0,0);
      acc[1] = __builtin_amdgcn_mfma_f32_16x16x32_bf16(a1, b, acc[1], 0,0,0);
    }
    float bb = b2[n];
    #pragma unroll
    for (int mt = 0; mt < 2; mt++)
      #pragma unroll
      for (int r = 0; r < 4; r++)
        h2s[mt*16 + quad*4 + r][n] = f2bf(fmaxf(acc[mt][r] + bb, 0.f));
  }
  __syncthreads();

  // ---- Phase 3: logits = h2 @ w3 + b3 -> lgs ----
  {
    f32x4 acc[2];
    acc[0] = (f32x4){0.f,0.f,0.f,0.f}; acc[1] = acc[0];
    const int n = wave*16 + l16;
    for (int k0 = 0; k0 < 64; k0 += 32){
      bf16x8 b  = *(const bf16x8*)(w3t + (size_t)n*64 + k0 + quad*8);
      bf16x8 a0 = *(const bf16x8*)&h2s[l16     ][k0 + quad*8];
      bf16x8 a1 = *(const bf16x8*)&h2s[16 + l16][k0 + quad*8];
      acc[0] = __builtin_amdgcn_mfma_f32_16x16x32_bf16(a0, b, acc[0], 0,0,0);
      acc[1] = __builtin_amdgcn_mfma_f32_16x16x32_bf16(a1, b, acc[1], 0,0,0);
    }
    float bb = b3[n];
    #pragma unroll
    for (int mt = 0; mt < 2; mt++)
      #pragma unroll
      for (int r = 0; r < 4; r++)
        lgs[mt*16 + quad*4 + r][n] = f2bf(acc[mt][r] + bb);
  }
  __syncthreads();

  // ---- Phase 4: logitsP = logits @ relu(2P) -> h2s ----
  {
    f32x4 acc[2];
    acc[0] = (f32x4){0.f,0.f,0.f,0.f}; acc[1] = acc[0];
    const int n = wave*16 + l16;
    for (int k0 = 0; k0 < 64; k0 += 32){
      bf16x8 b  = *(const bf16x8*)(Pt + (size_t)n*64 + k0 + quad*8);
      bf16x8 a0 = *(const bf16x8*)&lgs[l16     ][k0 + quad*8];
      bf16x8 a1 = *(const bf16x8*)&lgs[16 + l16][k0 + quad*8];
      acc[0] = __builtin_amdgcn_mfma_f32_16x16x32_bf16(a0, b, acc[0], 0,0,0);
      acc[1] = __builtin_amdgcn_mfma_f32_16x16x32_bf16(a1, b, acc[1], 0,0,0);
    }
    #pragma unroll
    for (int mt = 0; mt < 2; mt++)
      #pragma unroll
      for (int r = 0; r < 4; r++)
        h2s[mt*16 + quad*4 + r][n] = f2bf(acc[mt][r]);
  }
  __syncthreads();

  {
    int row = t >> 3, c0 = (t & 7) * 8;
    int gm = m0 + row;
    if (gm < M){
      *(bf16x8*)(lgb  + (size_t)gm*64 + c0) = *(const bf16x8*)&lgs[row][c0];
      *(bf16x8*)(lgpb + (size_t)gm*64 + c0) = *(const bf16x8*)&h2s[row][c0];
    }
  }
}

// ---------------- generic tiled fp32 GEMM, 64x64 tile ----------------
template<bool BIAS, bool RELU, bool RESID, bool BF16OUT>
__global__ __launch_bounds__(256) void gemm_k(const float* __restrict__ A, const float* __restrict__ B,
    const float* __restrict__ bias, const float* __restrict__ extra,
    float* __restrict__ C, short* __restrict__ Cb,
    int M, int N, int K, float beta){
  __shared__ float As[16][68];
  __shared__ float Bs[16][68];
  const int n0 = blockIdx.x*64, m0 = blockIdx.y*64;
  const int t = threadIdx.x;
  const int tx = t & 15, ty = t >> 4;
  float acc[4][4] = {{0.f}};
  for (int k0 = 0; k0 < K; k0 += 16){
    {
      int row = t >> 2, kq = t & 3;
      int gm = m0 + row;
      float4 a4 = make_float4(0.f,0.f,0.f,0.f);
      if (gm < M) a4 = *(const float4*)(A + (size_t)gm*K + k0 + kq*4);
      As[kq*4+0][row] = a4.x; As[kq*4+1][row] = a4.y;
      As[kq*4+2][row] = a4.z; As[kq*4+3][row] = a4.w;
    }
    {
      int kk = t >> 4, nq = t & 15;
      float4 b4 = *(const float4*)(B + (size_t)(k0+kk)*N + n0 + nq*4);
      *(float4*)&Bs[kk][nq*4] = b4;
    }
    __syncthreads();
    #pragma unroll
    for (int kk=0; kk<16; kk++){
      float4 a4 = *(const float4*)&As[kk][ty*4];
      float4 b4 = *(const float4*)&Bs[kk][tx*4];
      acc[0][0] += a4.x*b4.x; acc[0][1] += a4.x*b4.y; acc[0][2] += a4.x*b4.z; acc[0][3] += a4.x*b4.w;
      acc[1][0] += a4.y*b4.x; acc[1][1] += a4.y*b4.y; acc[1][2] += a4.y*b4.z; acc[1][3] += a4.y*b4.w;
      acc[2][0] += a4.z*b4.x; acc[2][1] += a4.z*b4.y; acc[2][2] += a4.z*b4.z; acc[2][3] += a4.z*b4.w;
      acc[3][0] += a4.w*b4.x; acc[3][1] += a4.w*b4.y; acc[3][2] += a4.w*b4.z; acc[3][3] += a4.w*b4.w;
    }
    __syncthreads();
  }
  const int nc = n0 + tx*4;
  float4 bb = make_float4(0.f,0.f,0.f,0.f);
  if (BIAS) bb = *(const float4*)(bias + nc);
  #pragma unroll
  for (int i=0;i<4;i++){
    int gm = m0 + ty*4 + i;
    if (gm >= M) continue;
    float4 v = make_float4(acc[i][0], acc[i][1], acc[i][2], acc[i][3]);
    if (RESID){
      float4 ex = *(const float4*)(extra + (size_t)gm*N + nc);
      float ob = 1.f - beta;
      v.x = beta*v.x + ob*ex.x; v.y = beta*v.y + ob*ex.y;
      v.z = beta*v.z + ob*ex.z; v.w = beta*v.w + ob*ex.w;
    }
    if (BIAS){ v.x += bb.x; v.y += bb.y; v.z += bb.z; v.w += bb.w; }
    if (RELU){
      v.x = fmaxf(v.x,0.f); v.y = fmaxf(v.y,0.f);
      v.z = fmaxf(v.z,0.f); v.w = fmaxf(v.w,0.f);
    }
    if (BF16OUT){
      short4 sv;
      sv.x = f2bf(v.x); sv.y = f2bf(v.y); sv.z = f2bf(v.z); sv.w = f2bf(v.w);
      *(short4*)(Cb + (size_t)gm*N + nc) = sv;
    } else {
      *(float4*)(C + (size_t)gm*N + nc) = v;
    }
  }
}

// ---------------- ew: 16 lanes/edge, bf16 gathers + stats ----------------
__global__ __launch_bounds__(256) void ew_k(const short* __restrict__ lgb, const short* __restrict__ lgpb,
    const int* __restrict__ row, const int* __restrict__ col,
    float* __restrict__ ew, float* __restrict__ scal, int E){
  const int t = threadIdx.x;
  const int lane = t & 63, wid = t >> 6;
  const int g = lane >> 4, q = lane & 15;
  const int gw = blockIdx.x*4 + wid;
  const int stride = gridDim.x*4*4;
  float s = 0.f, ss = 0.f;
  for (int e = gw*4 + g; e < E; e += stride){
    int r = row[e], c = col[e];
    short4 a = *(const short4*)(lgb  + (size_t)r*64 + q*4);
    short4 b = *(const short4*)(lgpb + (size_t)c*64 + q*4);
    float v = bf2f(a.x)*bf2f(b.x) + bf2f(a.y)*bf2f(b.y)
            + bf2f(a.z)*bf2f(b.z) + bf2f(a.w)*bf2f(b.w);
    v += __shfl_xor(v, 1); v += __shfl_xor(v, 2);
    v += __shfl_xor(v, 4); v += __shfl_xor(v, 8);
    if (q == 0){ ew[e] = v; s += v; ss += v*v; }
  }
  s  += __shfl_xor(s, 16);  s  += __shfl_xor(s, 32);
  ss += __shfl_xor(ss, 16); ss += __shfl_xor(ss, 32);
  __shared__ float ls[4], lss[4];
  if (lane == 0){ ls[wid] = s; lss[wid] = ss; }
  __syncthreads();
  if (t == 0){
    atomicAdd(&scal[0], ls[0]+ls[1]+ls[2]+ls[3]);
    atomicAdd(&scal[1], lss[0]+lss[1]+lss[2]+lss[3]);
  }
}

__global__ void finalize_k(float* scal, int E){
  double sum = (double)scal[0], sumsq = (double)scal[1];
  double mean = sum / (double)E;
  double var  = (sumsq - sum*sum/(double)E) / (double)(E-1);
  scal[2] = (float)mean;
  scal[3] = (float)sqrt(1e-4 / var);
}

// normalize ew, accumulate float degree at col, int count at col (for CSR)
__global__ __launch_bounds__(256) void ewnorm_k(float* __restrict__ ew, const int* __restrict__ col,
    float* __restrict__ deg, int* __restrict__ cnt, const float* __restrict__ scal, int E){
  int e = blockIdx.x*256 + threadIdx.x;
  if (e < E){
    float w = (ew[e] - scal[2]) * scal[3] + 1.0f;
    ew[e] = w;
    int c = col[e];
    atomicAdd(&deg[c], w);
    atomicAdd(&cnt[c], 1);
  }
}

__global__ __launch_bounds__(256) void dinv_k(float* __restrict__ deg, int n){
  int i = blockIdx.x*256 + threadIdx.x;
  if (i < n){ float d = deg[i]; deg[i] = (d > 0.f) ? rsqrtf(d) : 0.f; }
}

// ---------------- multi-block exclusive scan (3 phases) ----------------
// Phase 1: per-block (1024-elem chunk) sums
__global__ __launch_bounds__(256) void scan_sums_k(const int* __restrict__ cnt, int* __restrict__ bsum, int n){
  __shared__ int s[256];
  const int t = threadIdx.x;
  int i = blockIdx.x*1024 + t*4;
  int4 v = make_int4(0,0,0,0);
  if (i + 3 < n) v = *(const int4*)(cnt + i);
  else {
    if (i   < n) v.x = cnt[i];
    if (i+1 < n) v.y = cnt[i+1];
    if (i+2 < n) v.z = cnt[i+2];
    if (i+3 < n) v.w = cnt[i+3];
  }
  s[t] = v.x + v.y + v.z + v.w;
  __syncthreads();
  for (int st = 128; st; st >>= 1){
    if (t < st) s[t] += s[t + st];
    __syncthreads();
  }
  if (t == 0) bsum[blockIdx.x] = s[0];
}

// Phase 2: exclusive scan of block sums (nb <= 64), single wave
__global__ __launch_bounds__(64) void scan_bsum_k(int* __restrict__ bsum, int nb){
  int t = threadIdx.x;
  int own = (t < nb) ? bsum[t] : 0;
  int v = own;
  #pragma unroll
  for (int off = 1; off < 64; off <<= 1){
    int o = __shfl_up(v, off, 64);
    if (t >= off) v += o;
  }
  if (t < nb) bsum[t] = v - own;   // exclusive
}

// Phase 3: block-local scan + base -> off, cursor; off[n] = total (constant E)
__global__ __launch_bounds__(256) void scan_final_k(const int* __restrict__ cnt, const int* __restrict__ bsum,
    int* __restrict__ off, int* __restrict__ cursor, int n, int total){
  __shared__ int s[256];
  const int t = threadIdx.x;
  int i = blockIdx.x*1024 + t*4;
  int4 v = make_int4(0,0,0,0);
  if (i + 3 < n) v = *(const int4*)(cnt + i);
  else {
    if (i   < n) v.x = cnt[i];
    if (i+1 < n) v.y = cnt[i+1];
    if (i+2 < n) v.z = cnt[i+2];
    if (i+3 < n) v.w = cnt[i+3];
  }
  int tsum = v.x + v.y + v.z + v.w;
  s[t] = tsum;
  __syncthreads();
  // Hillis-Steele inclusive scan over 256 thread sums
  #pragma unroll
  for (int st = 1; st < 256; st <<= 1){
    int a = (t >= st) ? s[t - st] : 0;
    __syncthreads();
    s[t] += a;
    __syncthreads();
  }
  int base = s[t] - tsum + bsum[blockIdx.x];
  int o0 = base, o1 = o0 + v.x, o2 = o1 + v.y, o3 = o2 + v.z;
  if (i   < n){ off[i]   = o0; cursor[i]   = o0; }
  if (i+1 < n){ off[i+1] = o1; cursor[i+1] = o1; }
  if (i+2 < n){ off[i+2] = o2; cursor[i+2] = o2; }
  if (i+3 < n){ off[i+3] = o3; cursor[i+3] = o3; }
  if (blockIdx.x == 0 && t == 0) off[n] = total;
}

// bucket edges by destination; store src and final edge weight dinv[r]*w*dinv[c]
__global__ __launch_bounds__(256) void scatter_k(const int* __restrict__ row, const int* __restrict__ col,
    const float* __restrict__ ew, const float* __restrict__ dinv,
    int* __restrict__ cursor, int* __restrict__ csr_src, float* __restrict__ csr_w, int E){
  int e = blockIdx.x*256 + threadIdx.x;
  if (e < E){
    int r = row[e], c = col[e];
    int slot = atomicAdd(&cursor[c], 1);
    csr_src[slot] = r;
    csr_w[slot]  = dinv[r] * ew[e] * dinv[c];
  }
}

// CSR gather aggregation from bf16 h: wave per node, 2 channels/lane
__global__ __launch_bounds__(256) void agg_gather_k(const short* __restrict__ hb,
    const int* __restrict__ off, const int* __restrict__ src, const float* __restrict__ w,
    const float* __restrict__ dinv, float* __restrict__ agg, int Nn){
  int n = blockIdx.x*4 + (threadIdx.x >> 6);
  int lane = threadIdx.x & 63;
  if (n >= Nn) return;
  float d = dinv[n];
  short2 hv = *(const short2*)(hb + (size_t)n*128 + lane*2);
  float acc0 = d*d*bf2f(hv.x), acc1 = d*d*bf2f(hv.y);
  int s = off[n], e = off[n+1];
  int j = s;
  for (; j + 1 < e; j += 2){
    int r0 = src[j], r1 = src[j+1];
    float w0 = w[j], w1 = w[j+1];
    short2 h0 = *(const short2*)(hb + (size_t)r0*128 + lane*2);
    short2 h1 = *(const short2*)(hb + (size_t)r1*128 + lane*2);
    acc0 += w0*bf2f(h0.x) + w1*bf2f(h1.x);
    acc1 += w0*bf2f(h0.y) + w1*bf2f(h1.y);
  }
  if (j < e){
    short2 h0 = *(const short2*)(hb + (size_t)src[j]*128 + lane*2);
    float w0 = w[j];
    acc0 += w0*bf2f(h0.x); acc1 += w0*bf2f(h0.y);
  }
  *(float2*)(agg + (size_t)n*128 + lane*2) = make_float2(acc0, acc1);
}

extern "C" void kernel_launch(void* const* d_in, const int* in_sizes, int n_in,
                              void* d_out, int out_size, void* d_ws, size_t ws_size,
                              hipStream_t stream){
  const float* x      = (const float*)d_in[0];
  const int*   ei     = (const int*)  d_in[1];
  const float* w1     = (const float*)d_in[2];
  const float* b1     = (const float*)d_in[3];
  const float* w2     = (const float*)d_in[4];
  const float* b2     = (const float*)d_in[5];
  const float* w3     = (const float*)d_in[6];
  const float* b3     = (const float*)d_in[7];
  const float* pars   = (const float*)d_in[8];
  const float* lin0w  = (const float*)d_in[9];
  const float* lin0b  = (const float*)d_in[10];
  const float* lin1w  = (const float*)d_in[11];
  const float* lin1b  = (const float*)d_in[12];
  const float* cw1    = (const float*)d_in[13];
  float* out          = (float*)d_out;

  float* ws = (float*)d_ws;
  // workspace layout (float-element offsets)
  int*   cnt     = (int*)(ws + 0);            //    50,000
  int*   off     = (int*)(ws + 50048);        //    50,001
  int*   cursor  = (int*)(ws + 100096);       //    50,000
  int*   csr_src = (int*)(ws + 150144);       //   800,000
  float* csr_w   = ws + 950144;               //   800,000 (ends 1,750,144)
  int*   bsum    = (int*)(ws + 1750400);      //        64
  short* lgb     = (short*)(ws + 1800000);    // 3.2M shorts
  short* lgpb    = (short*)(ws + 3400000);    // 3.2M shorts
  float* ew      = ws + 5000000;              //   800,000
  float* deg     = ws + 5800000;              //    50,000
  float* scal    = ws + 5850048;              //        16
  short* bufAb   = (short*)(ws + 5900000);    // 6.4M shorts
  short* bufCb   = (short*)(ws + 9100000);    // 6.4M shorts
  float* bufAgg  = ws + 12300000;             // 6,400,000
  float* bufB    = ws + 18700000;             // 6,400,000
  // bf16 transposed MLP weights overlay on bufB (consumed before bufB written):
  short* w1t     = (short*)bufB;
  short* w2t     = w1t + 65536;
  short* w3t     = w2t + 32768;
  short* Pt      = w3t + 4096;

  const int Mn = NN, E = NE;
  const int* erow = ei;
  const int* ecol = ei + E;
  const float beta0 = 0.69314718055994530942f;  // ln(2)
  const float beta1 = 0.40546510810816438198f;  // ln(1.5)
  const int nScanB = (Mn + 1023) / 1024;        // 49 <= 64

  // 1) init + weight prep
  init_k<<<(Mn+255)/256, 256, 0, stream>>>(deg, scal, Mn);
  prep_k<<<(106496+255)/256, 256, 0, stream>>>(w1, w2, w3, pars, w1t, w2t, w3t, Pt);
  // 2) fused bf16-MFMA MLP chain -> lgb, lgpb (bf16)
  mlp_mfma_k<<<(Mn+31)/32, 256, 0, stream>>>(x, w1t, b1, w2t, b2, w3t, b3, Pt,
                                             lgb, lgpb, Mn);
  zero_cnt_k<<<(Mn+255)/256, 256, 0, stream>>>(cnt, Mn);
  // 3) ew + stats
  ew_k<<<2048, 256, 0, stream>>>(lgb, lgpb, erow, ecol, ew, scal, E);
  finalize_k<<<1, 1, 0, stream>>>(scal, E);
  // 4) normalize ew, degree + count accumulation; dinv
  ewnorm_k<<<(E+255)/256, 256, 0, stream>>>(ew, ecol, deg, cnt, scal, E);
  dinv_k<<<(Mn+255)/256, 256, 0, stream>>>(deg, Mn);
  // 5) CSR build: multi-block scan + bucket scatter
  scan_sums_k<<<nScanB, 256, 0, stream>>>(cnt, bsum, Mn);
  scan_bsum_k<<<1, 64, 0, stream>>>(bsum, nScanB);
  scan_final_k<<<nScanB, 256, 0, stream>>>(cnt, bsum, off, cursor, Mn, E);
  scatter_k<<<(E+255)/256, 256, 0, stream>>>(erow, ecol, ew, deg, cursor, csr_src, csr_w, E);
  // 6) x0 = relu(x@lin0w + lin0b) -> bufAb (bf16)
  dim3 g128(2, (Mn+63)/64);
  gemm_k<true,true,false,true><<<g128, 256, 0, stream>>>(x, lin0w, lin0b, nullptr, nullptr, bufAb, Mn, 128, 128, 0.f);
  // 7) layer 0: gather agg from bufAb; hnext -> bufCb (bf16)
  agg_gather_k<<<(Mn+3)/4, 256, 0, stream>>>(bufAb, off, csr_src, csr_w, deg, bufAgg, Mn);
  gemm_k<false,true,true,true><<<g128, 256, 0, stream>>>(bufAgg, cw1, nullptr, bufAgg, nullptr, bufCb, Mn, 128, 128, beta0);
  // 8) layer 1: gather agg from bufCb; hnext -> bufB (fp32, feeds final GEMM)
  agg_gather_k<<<(Mn+3)/4, 256, 0, stream>>>(bufCb, off, csr_src, csr_w, deg, bufAgg, Mn);
  gemm_k<false,true,true,false><<<g128, 256, 0, stream>>>(bufAgg, cw1 + 128*128, nullptr, bufAgg, bufB, nullptr, Mn, 128, 128, beta1);
  // 9) out = bufB @ lin1w + lin1b
  gemm_k<true,false,false,false><<<dim3(1,(Mn+63)/64), 256, 0, stream>>>(bufB, lin1w, lin1b, nullptr, out, nullptr, Mn, 64, 128, 0.f);
}

// Round 6
// 507.311 us; speedup vs baseline: 2.6814x; 1.1528x over previous
//
#include <hip/hip_runtime.h>
#include <hip/hip_bf16.h>
#include <math.h>

#define NN 50000
#define NE 800000

typedef __attribute__((ext_vector_type(8))) short bf16x8;
typedef __attribute__((ext_vector_type(4))) float f32x4;

__device__ __forceinline__ short f2bf(float f){
  unsigned u = __float_as_uint(f);
  unsigned r = (u + 0x7fffu + ((u >> 16) & 1u)) >> 16;
  return (short)r;
}
__device__ __forceinline__ float bf2f(short s){
  return __uint_as_float(((unsigned)(unsigned short)s) << 16);
}

// ---------------- init: deg=1 (self loop), zero stat scalars ----------------
__global__ __launch_bounds__(256) void init_k(float* __restrict__ deg, float* __restrict__ scal, int n){
  int i = blockIdx.x*256 + threadIdx.x;
  if (i < n) deg[i] = 1.0f;
  if (blockIdx.x == 0 && threadIdx.x < 16) scal[threadIdx.x] = 0.0f;
}

__global__ __launch_bounds__(256) void zero_cnt_k(int* __restrict__ cnt, int n){
  int i = blockIdx.x*256 + threadIdx.x;
  if (i < n) cnt[i] = 0;
}

// ---------------- weight prep: transpose + bf16 convert (MLP + GCN weights) ----------------
__global__ __launch_bounds__(256) void prep_k(const float* __restrict__ w1,
    const float* __restrict__ w2, const float* __restrict__ w3, const float* __restrict__ pars,
    const float* __restrict__ lin0w, const float* __restrict__ cw1, const float* __restrict__ lin1w,
    short* __restrict__ w1t, short* __restrict__ w2t, short* __restrict__ w3t, short* __restrict__ Pt,
    short* __restrict__ lin0wt, short* __restrict__ cw1t0, short* __restrict__ cw1t1,
    short* __restrict__ lin1wt){
  int idx = blockIdx.x*256 + threadIdx.x;
  if (idx < 65536){
    int n = idx >> 7, k = idx & 127;
    w1t[idx] = f2bf(w1[k*512 + n]);
  } else if (idx < 98304){
    int i = idx - 65536; int n = i >> 9, k = i & 511;
    w2t[i] = f2bf(w2[k*64 + n]);
  } else if (idx < 102400){
    int i = idx - 98304; int n = i >> 6, k = i & 63;
    w3t[i] = f2bf(w3[k*64 + n]);
  } else if (idx < 106496){
    int i = idx - 102400; int n = i >> 6, k = i & 63;
    Pt[i] = f2bf(fmaxf(2.f*pars[k*64 + n], 0.f));
  } else if (idx < 122880){
    int i = idx - 106496; int n = i >> 7, k = i & 127;
    lin0wt[i] = f2bf(lin0w[k*128 + n]);
  } else if (idx < 139264){
    int i = idx - 122880; int n = i >> 7, k = i & 127;
    cw1t0[i] = f2bf(cw1[k*128 + n]);
  } else if (idx < 155648){
    int i = idx - 139264; int n = i >> 7, k = i & 127;
    cw1t1[i] = f2bf(cw1[16384 + k*128 + n]);
  } else if (idx < 163840){
    int i = idx - 155648; int n = i >> 7, k = i & 127;   // n in [0,64)
    lin1wt[i] = f2bf(lin1w[k*64 + n]);
  }
}

// ---------------- fused bf16-MFMA MLP chain -> bf16 logits / logitsP (+ xb dump) ----------------
__global__ __launch_bounds__(256) void mlp_mfma_k(
    const float* __restrict__ x,
    const short* __restrict__ w1t, const float* __restrict__ b1,
    const short* __restrict__ w2t, const float* __restrict__ b2,
    const short* __restrict__ w3t, const float* __restrict__ b3,
    const short* __restrict__ Pt,
    short* __restrict__ lgb, short* __restrict__ lgpb, short* __restrict__ xb, int M)
{
  __shared__ short xs [32][136];
  __shared__ short h1s[32][520];
  __shared__ short h2s[32][72];   // phase2 out; reused as lgpb staging in phase 4
  __shared__ short lgs[32][72];
  const int t = threadIdx.x;
  const int wave = t >> 6, lane = t & 63;
  const int quad = lane >> 4, l16 = lane & 15;
  const int m0 = blockIdx.x * 32;

  for (int task = t; task < 512; task += 256){
    int row = task >> 4, c0 = (task & 15) * 8;
    float4 v0 = make_float4(0,0,0,0), v1 = v0;
    if (m0 + row < M){
      v0 = *(const float4*)(x + (size_t)(m0+row)*128 + c0);
      v1 = *(const float4*)(x + (size_t)(m0+row)*128 + c0 + 4);
    }
    bf16x8 s;
    s[0]=f2bf(v0.x); s[1]=f2bf(v0.y); s[2]=f2bf(v0.z); s[3]=f2bf(v0.w);
    s[4]=f2bf(v1.x); s[5]=f2bf(v1.y); s[6]=f2bf(v1.z); s[7]=f2bf(v1.w);
    *(bf16x8*)&xs[row][c0] = s;
  }
  __syncthreads();

  // ---- Phase 1: h1 = relu(x @ w1 + b1) ----
  {
    f32x4 acc[2][8];
    #pragma unroll
    for (int mt=0;mt<2;mt++)
      #pragma unroll
      for (int nt=0;nt<8;nt++) acc[mt][nt] = (f32x4){0.f,0.f,0.f,0.f};
    for (int k0 = 0; k0 < 128; k0 += 32){
      bf16x8 a0 = *(const bf16x8*)&xs[l16     ][k0 + quad*8];
      bf16x8 a1 = *(const bf16x8*)&xs[16 + l16][k0 + quad*8];
      #pragma unroll
      for (int nt = 0; nt < 8; nt++){
        int n = wave*128 + nt*16 + l16;
        bf16x8 b = *(const bf16x8*)(w1t + (size_t)n*128 + k0 + quad*8);
        acc[0][nt] = __builtin_amdgcn_mfma_f32_16x16x32_bf16(a0, b, acc[0][nt], 0,0,0);
        acc[1][nt] = __builtin_amdgcn_mfma_f32_16x16x32_bf16(a1, b, acc[1][nt], 0,0,0);
      }
    }
    #pragma unroll
    for (int nt = 0; nt < 8; nt++){
      int n = wave*128 + nt*16 + l16;
      float bb = b1[n];
      #pragma unroll
      for (int mt = 0; mt < 2; mt++){
        #pragma unroll
        for (int r = 0; r < 4; r++){
          int row = mt*16 + quad*4 + r;
          h1s[row][n] = f2bf(fmaxf(acc[mt][nt][r] + bb, 0.f));
        }
      }
    }
  }
  __syncthreads();

  // ---- Phase 2: h2 = relu(h1 @ w2 + b2) ----
  {
    f32x4 acc[2];
    acc[0] = (f32x4){0.f,0.f,0.f,0.f}; acc[1] = acc[0];
    const int n = wave*16 + l16;
    for (int k0 = 0; k0 < 512; k0 += 32){
      bf16x8 b  = *(const bf16x8*)(w2t + (size_t)n*512 + k0 + quad*8);
      bf16x8 a0 = *(const bf16x8*)&h1s[l16     ][k0 + quad*8];
      bf16x8 a1 = *(const bf16x8*)&h1s[16 + l16][k0 + quad*8];
      acc[0] = __builtin_amdgcn_mfma_f32_16x16x32_bf16(a0, b, acc[0], 0,0,0);
      acc[1] = __builtin_amdgcn_mfma_f32_16x16x32_bf16(a1, b, acc[1], 0,0,0);
    }
    float bb = b2[n];
    #pragma unroll
    for (int mt = 0; mt < 2; mt++)
      #pragma unroll
      for (int r = 0; r < 4; r++)
        h2s[mt*16 + quad*4 + r][n] = f2bf(fmaxf(acc[mt][r] + bb, 0.f));
  }
  __syncthreads();

  // ---- Phase 3: logits = h2 @ w3 + b3 -> lgs ----
  {
    f32x4 acc[2];
    acc[0] = (f32x4){0.f,0.f,0.f,0.f}; acc[1] = acc[0];
    const int n = wave*16 + l16;
    for (int k0 = 0; k0 < 64; k0 += 32){
      bf16x8 b  = *(const bf16x8*)(w3t + (size_t)n*64 + k0 + quad*8);
      bf16x8 a0 = *(const bf16x8*)&h2s[l16     ][k0 + quad*8];
      bf16x8 a1 = *(const bf16x8*)&h2s[16 + l16][k0 + quad*8];
      acc[0] = __builtin_amdgcn_mfma_f32_16x16x32_bf16(a0, b, acc[0], 0,0,0);
      acc[1] = __builtin_amdgcn_mfma_f32_16x16x32_bf16(a1, b, acc[1], 0,0,0);
    }
    float bb = b3[n];
    #pragma unroll
    for (int mt = 0; mt < 2; mt++)
      #pragma unroll
      for (int r = 0; r < 4; r++)
        lgs[mt*16 + quad*4 + r][n] = f2bf(acc[mt][r] + bb);
  }
  __syncthreads();

  // ---- Phase 4: logitsP = logits @ relu(2P) -> h2s ----
  {
    f32x4 acc[2];
    acc[0] = (f32x4){0.f,0.f,0.f,0.f}; acc[1] = acc[0];
    const int n = wave*16 + l16;
    for (int k0 = 0; k0 < 64; k0 += 32){
      bf16x8 b  = *(const bf16x8*)(Pt + (size_t)n*64 + k0 + quad*8);
      bf16x8 a0 = *(const bf16x8*)&lgs[l16     ][k0 + quad*8];
      bf16x8 a1 = *(const bf16x8*)&lgs[16 + l16][k0 + quad*8];
      acc[0] = __builtin_amdgcn_mfma_f32_16x16x32_bf16(a0, b, acc[0], 0,0,0);
      acc[1] = __builtin_amdgcn_mfma_f32_16x16x32_bf16(a1, b, acc[1], 0,0,0);
    }
    #pragma unroll
    for (int mt = 0; mt < 2; mt++)
      #pragma unroll
      for (int r = 0; r < 4; r++)
        h2s[mt*16 + quad*4 + r][n] = f2bf(acc[mt][r]);
  }
  __syncthreads();

  {
    int row = t >> 3, c0 = (t & 7) * 8;
    int gm = m0 + row;
    if (gm < M){
      *(bf16x8*)(lgb  + (size_t)gm*64 + c0) = *(const bf16x8*)&lgs[row][c0];
      *(bf16x8*)(lgpb + (size_t)gm*64 + c0) = *(const bf16x8*)&h2s[row][c0];
    }
  }
  // dump staged bf16 x -> xb (feeds x0 GEMM)
  for (int task = t; task < 512; task += 256){
    int row = task >> 4, c0 = (task & 15) * 8;
    int gm = m0 + row;
    if (gm < M)
      *(bf16x8*)(xb + (size_t)gm*128 + c0) = *(const bf16x8*)&xs[row][c0];
  }
}

// ---------------- bf16 MFMA GEMM: C[M][N] = EPI(A[M][128] @ Bt[N][128]^T) ----------------
// NT = column-tiles of 16 per wave (NT=2 -> N=128, NT=1 -> N=64). K fixed at 128.
// RESID: v = beta*acc + (1-beta)*extra[m][n] (extra bf16). bias optional (runtime null check).
template<int NT, bool RELU, bool RESID, bool BF16OUT>
__global__ __launch_bounds__(256) void bgemm_k(
    const short* __restrict__ A, const short* __restrict__ Bt,
    const float* __restrict__ bias, const short* __restrict__ extra,
    float* __restrict__ C, short* __restrict__ Cb, int M, float beta)
{
  const int N = NT*64;
  __shared__ short As[32][136];
  const int t = threadIdx.x;
  const int wave = t >> 6, lane = t & 63;
  const int quad = lane >> 4, l16 = lane & 15;
  const int m0 = blockIdx.x * 32;

  for (int task = t; task < 512; task += 256){
    int row = task >> 4, c0 = (task & 15) * 8;
    bf16x8 v = {0,0,0,0,0,0,0,0};
    if (m0 + row < M) v = *(const bf16x8*)(A + (size_t)(m0+row)*128 + c0);
    *(bf16x8*)&As[row][c0] = v;
  }
  __syncthreads();

  f32x4 acc[2][NT];
  #pragma unroll
  for (int mt=0;mt<2;mt++)
    #pragma unroll
    for (int nt=0;nt<NT;nt++) acc[mt][nt] = (f32x4){0.f,0.f,0.f,0.f};

  #pragma unroll
  for (int k0 = 0; k0 < 128; k0 += 32){
    bf16x8 a0 = *(const bf16x8*)&As[l16     ][k0 + quad*8];
    bf16x8 a1 = *(const bf16x8*)&As[16 + l16][k0 + quad*8];
    #pragma unroll
    for (int nt = 0; nt < NT; nt++){
      int n = (wave*NT + nt)*16 + l16;
      bf16x8 b = *(const bf16x8*)(Bt + (size_t)n*128 + k0 + quad*8);
      acc[0][nt] = __builtin_amdgcn_mfma_f32_16x16x32_bf16(a0, b, acc[0][nt], 0,0,0);
      acc[1][nt] = __builtin_amdgcn_mfma_f32_16x16x32_bf16(a1, b, acc[1][nt], 0,0,0);
    }
  }

  #pragma unroll
  for (int nt = 0; nt < NT; nt++){
    int n = (wave*NT + nt)*16 + l16;
    float bb = (bias != nullptr) ? bias[n] : 0.f;
    #pragma unroll
    for (int mt = 0; mt < 2; mt++){
      #pragma unroll
      for (int r = 0; r < 4; r++){
        int gm = m0 + mt*16 + quad*4 + r;
        if (gm >= M) continue;
        float v = acc[mt][nt][r];
        if (RESID){
          float ex = bf2f(extra[(size_t)gm*N + n]);
          v = beta*v + (1.f - beta)*ex;
        }
        v += bb;
        if (RELU) v = fmaxf(v, 0.f);
        if (BF16OUT) Cb[(size_t)gm*N + n] = f2bf(v);
        else         C [(size_t)gm*N + n] = v;
      }
    }
  }
}

// ---------------- ew: 16 lanes/edge, bf16 gathers + stats ----------------
__global__ __launch_bounds__(256) void ew_k(const short* __restrict__ lgb, const short* __restrict__ lgpb,
    const int* __restrict__ row, const int* __restrict__ col,
    float* __restrict__ ew, float* __restrict__ scal, int E){
  const int t = threadIdx.x;
  const int lane = t & 63, wid = t >> 6;
  const int g = lane >> 4, q = lane & 15;
  const int gw = blockIdx.x*4 + wid;
  const int stride = gridDim.x*4*4;
  float s = 0.f, ss = 0.f;
  for (int e = gw*4 + g; e < E; e += stride){
    int r = row[e], c = col[e];
    short4 a = *(const short4*)(lgb  + (size_t)r*64 + q*4);
    short4 b = *(const short4*)(lgpb + (size_t)c*64 + q*4);
    float v = bf2f(a.x)*bf2f(b.x) + bf2f(a.y)*bf2f(b.y)
            + bf2f(a.z)*bf2f(b.z) + bf2f(a.w)*bf2f(b.w);
    v += __shfl_xor(v, 1); v += __shfl_xor(v, 2);
    v += __shfl_xor(v, 4); v += __shfl_xor(v, 8);
    if (q == 0){ ew[e] = v; s += v; ss += v*v; }
  }
  s  += __shfl_xor(s, 16);  s  += __shfl_xor(s, 32);
  ss += __shfl_xor(ss, 16); ss += __shfl_xor(ss, 32);
  __shared__ float ls[4], lss[4];
  if (lane == 0){ ls[wid] = s; lss[wid] = ss; }
  __syncthreads();
  if (t == 0){
    atomicAdd(&scal[0], ls[0]+ls[1]+ls[2]+ls[3]);
    atomicAdd(&scal[1], lss[0]+lss[1]+lss[2]+lss[3]);
  }
}

__global__ void finalize_k(float* scal, int E){
  double sum = (double)scal[0], sumsq = (double)scal[1];
  double mean = sum / (double)E;
  double var  = (sumsq - sum*sum/(double)E) / (double)(E-1);
  scal[2] = (float)mean;
  scal[3] = (float)sqrt(1e-4 / var);
}

// normalize ew, accumulate float degree at col, int count at col (for CSR)
__global__ __launch_bounds__(256) void ewnorm_k(float* __restrict__ ew, const int* __restrict__ col,
    float* __restrict__ deg, int* __restrict__ cnt, const float* __restrict__ scal, int E){
  int e = blockIdx.x*256 + threadIdx.x;
  if (e < E){
    float w = (ew[e] - scal[2]) * scal[3] + 1.0f;
    ew[e] = w;
    int c = col[e];
    atomicAdd(&deg[c], w);
    atomicAdd(&cnt[c], 1);
  }
}

__global__ __launch_bounds__(256) void dinv_k(float* __restrict__ deg, int n){
  int i = blockIdx.x*256 + threadIdx.x;
  if (i < n){ float d = deg[i]; deg[i] = (d > 0.f) ? rsqrtf(d) : 0.f; }
}

// ---------------- multi-block exclusive scan (3 phases) ----------------
__global__ __launch_bounds__(256) void scan_sums_k(const int* __restrict__ cnt, int* __restrict__ bsum, int n){
  __shared__ int s[256];
  const int t = threadIdx.x;
  int i = blockIdx.x*1024 + t*4;
  int4 v = make_int4(0,0,0,0);
  if (i + 3 < n) v = *(const int4*)(cnt + i);
  else {
    if (i   < n) v.x = cnt[i];
    if (i+1 < n) v.y = cnt[i+1];
    if (i+2 < n) v.z = cnt[i+2];
    if (i+3 < n) v.w = cnt[i+3];
  }
  s[t] = v.x + v.y + v.z + v.w;
  __syncthreads();
  for (int st = 128; st; st >>= 1){
    if (t < st) s[t] += s[t + st];
    __syncthreads();
  }
  if (t == 0) bsum[blockIdx.x] = s[0];
}

__global__ __launch_bounds__(64) void scan_bsum_k(int* __restrict__ bsum, int nb){
  int t = threadIdx.x;
  int own = (t < nb) ? bsum[t] : 0;
  int v = own;
  #pragma unroll
  for (int off = 1; off < 64; off <<= 1){
    int o = __shfl_up(v, off, 64);
    if (t >= off) v += o;
  }
  if (t < nb) bsum[t] = v - own;   // exclusive
}

__global__ __launch_bounds__(256) void scan_final_k(const int* __restrict__ cnt, const int* __restrict__ bsum,
    int* __restrict__ off, int* __restrict__ cursor, int n, int total){
  __shared__ int s[256];
  const int t = threadIdx.x;
  int i = blockIdx.x*1024 + t*4;
  int4 v = make_int4(0,0,0,0);
  if (i + 3 < n) v = *(const int4*)(cnt + i);
  else {
    if (i   < n) v.x = cnt[i];
    if (i+1 < n) v.y = cnt[i+1];
    if (i+2 < n) v.z = cnt[i+2];
    if (i+3 < n) v.w = cnt[i+3];
  }
  int tsum = v.x + v.y + v.z + v.w;
  s[t] = tsum;
  __syncthreads();
  #pragma unroll
  for (int st = 1; st < 256; st <<= 1){
    int a = (t >= st) ? s[t - st] : 0;
    __syncthreads();
    s[t] += a;
    __syncthreads();
  }
  int base = s[t] - tsum + bsum[blockIdx.x];
  int o0 = base, o1 = o0 + v.x, o2 = o1 + v.y, o3 = o2 + v.z;
  if (i   < n){ off[i]   = o0; cursor[i]   = o0; }
  if (i+1 < n){ off[i+1] = o1; cursor[i+1] = o1; }
  if (i+2 < n){ off[i+2] = o2; cursor[i+2] = o2; }
  if (i+3 < n){ off[i+3] = o3; cursor[i+3] = o3; }
  if (blockIdx.x == 0 && t == 0) off[n] = total;
}

// bucket edges by destination; store src and final edge weight dinv[r]*w*dinv[c]
__global__ __launch_bounds__(256) void scatter_k(const int* __restrict__ row, const int* __restrict__ col,
    const float* __restrict__ ew, const float* __restrict__ dinv,
    int* __restrict__ cursor, int* __restrict__ csr_src, float* __restrict__ csr_w, int E){
  int e = blockIdx.x*256 + threadIdx.x;
  if (e < E){
    int r = row[e], c = col[e];
    int slot = atomicAdd(&cursor[c], 1);
    csr_src[slot] = r;
    csr_w[slot]  = dinv[r] * ew[e] * dinv[c];
  }
}

// CSR gather aggregation from bf16 h: wave per node, 2 channels/lane, bf16 out
__global__ __launch_bounds__(256) void agg_gather_k(const short* __restrict__ hb,
    const int* __restrict__ off, const int* __restrict__ src, const float* __restrict__ w,
    const float* __restrict__ dinv, short* __restrict__ aggb, int Nn){
  int n = blockIdx.x*4 + (threadIdx.x >> 6);
  int lane = threadIdx.x & 63;
  if (n >= Nn) return;
  float d = dinv[n];
  short2 hv = *(const short2*)(hb + (size_t)n*128 + lane*2);
  float acc0 = d*d*bf2f(hv.x), acc1 = d*d*bf2f(hv.y);
  int s = off[n], e = off[n+1];
  int j = s;
  for (; j + 1 < e; j += 2){
    int r0 = src[j], r1 = src[j+1];
    float w0 = w[j], w1 = w[j+1];
    short2 h0 = *(const short2*)(hb + (size_t)r0*128 + lane*2);
    short2 h1 = *(const short2*)(hb + (size_t)r1*128 + lane*2);
    acc0 += w0*bf2f(h0.x) + w1*bf2f(h1.x);
    acc1 += w0*bf2f(h0.y) + w1*bf2f(h1.y);
  }
  if (j < e){
    short2 h0 = *(const short2*)(hb + (size_t)src[j]*128 + lane*2);
    float w0 = w[j];
    acc0 += w0*bf2f(h0.x); acc1 += w0*bf2f(h0.y);
  }
  short2 o; o.x = f2bf(acc0); o.y = f2bf(acc1);
  *(short2*)(aggb + (size_t)n*128 + lane*2) = o;
}

extern "C" void kernel_launch(void* const* d_in, const int* in_sizes, int n_in,
                              void* d_out, int out_size, void* d_ws, size_t ws_size,
                              hipStream_t stream){
  const float* x      = (const float*)d_in[0];
  const int*   ei     = (const int*)  d_in[1];
  const float* w1     = (const float*)d_in[2];
  const float* b1     = (const float*)d_in[3];
  const float* w2     = (const float*)d_in[4];
  const float* b2     = (const float*)d_in[5];
  const float* w3     = (const float*)d_in[6];
  const float* b3     = (const float*)d_in[7];
  const float* pars   = (const float*)d_in[8];
  const float* lin0w  = (const float*)d_in[9];
  const float* lin0b  = (const float*)d_in[10];
  const float* lin1w  = (const float*)d_in[11];
  const float* lin1b  = (const float*)d_in[12];
  const float* cw1    = (const float*)d_in[13];
  float* out          = (float*)d_out;

  float* ws = (float*)d_ws;
  // workspace layout (float-element offsets)
  int*   cnt     = (int*)(ws + 0);            //    50,000
  int*   off     = (int*)(ws + 50048);        //    50,001
  int*   cursor  = (int*)(ws + 100096);       //    50,000
  int*   csr_src = (int*)(ws + 150144);       //   800,000
  float* csr_w   = ws + 950144;               //   800,000 (ends 1,750,144)
  int*   bsum    = (int*)(ws + 1750400);      //        64
  short* lin0wt  = (short*)(ws + 1751000);    //  16,384 shorts
  short* cw1t0   = lin0wt + 16384;            //  16,384
  short* cw1t1   = cw1t0 + 16384;             //  16,384
  short* lin1wt  = cw1t1 + 16384;             //   8,192 (ends ws+1779672)
  short* lgb     = (short*)(ws + 1800000);    // 3.2M shorts
  short* lgpb    = (short*)(ws + 3400000);    // 3.2M shorts
  float* ew      = ws + 5000000;              //   800,000
  float* deg     = ws + 5800000;              //    50,000
  float* scal    = ws + 5850048;              //        16
  short* bufAb   = (short*)(ws + 5900000);    // 6.4M shorts (x0)
  short* bufCb   = (short*)(ws + 9100000);    // 6.4M shorts (h after layer0)
  short* aggb    = (short*)(ws + 12300000);   // 6.4M shorts (aggregation out)
  short* bufBb   = (short*)(ws + 15500000);   // 6.4M shorts (h after layer1)
  short* w1t     = (short*)(ws + 18700000);   // 106,496 shorts MLP weights
  short* w2t     = w1t + 65536;
  short* w3t     = w2t + 32768;
  short* Pt      = w3t + 4096;
  short* xb      = (short*)(ws + 18800000);   // 6.4M shorts (bf16 x) ends 22,000,000

  const int Mn = NN, E = NE;
  const int* erow = ei;
  const int* ecol = ei + E;
  const float beta0 = 0.69314718055994530942f;  // ln(2)
  const float beta1 = 0.40546510810816438198f;  // ln(1.5)
  const int nScanB = (Mn + 1023) / 1024;        // 49 <= 64
  const int nGB = (Mn + 31) / 32;               // bgemm grid

  // 1) init + weight prep
  init_k<<<(Mn+255)/256, 256, 0, stream>>>(deg, scal, Mn);
  prep_k<<<(163840+255)/256, 256, 0, stream>>>(w1, w2, w3, pars, lin0w, cw1, lin1w,
                                               w1t, w2t, w3t, Pt, lin0wt, cw1t0, cw1t1, lin1wt);
  // 2) fused bf16-MFMA MLP chain -> lgb, lgpb (bf16) + xb dump
  mlp_mfma_k<<<(Mn+31)/32, 256, 0, stream>>>(x, w1t, b1, w2t, b2, w3t, b3, Pt,
                                             lgb, lgpb, xb, Mn);
  zero_cnt_k<<<(Mn+255)/256, 256, 0, stream>>>(cnt, Mn);
  // 3) ew + stats
  ew_k<<<2048, 256, 0, stream>>>(lgb, lgpb, erow, ecol, ew, scal, E);
  finalize_k<<<1, 1, 0, stream>>>(scal, E);
  // 4) normalize ew, degree + count accumulation; dinv
  ewnorm_k<<<(E+255)/256, 256, 0, stream>>>(ew, ecol, deg, cnt, scal, E);
  dinv_k<<<(Mn+255)/256, 256, 0, stream>>>(deg, Mn);
  // 5) CSR build: multi-block scan + bucket scatter
  scan_sums_k<<<nScanB, 256, 0, stream>>>(cnt, bsum, Mn);
  scan_bsum_k<<<1, 64, 0, stream>>>(bsum, nScanB);
  scan_final_k<<<nScanB, 256, 0, stream>>>(cnt, bsum, off, cursor, Mn, E);
  scatter_k<<<(E+255)/256, 256, 0, stream>>>(erow, ecol, ew, deg, cursor, csr_src, csr_w, E);
  // 6) x0 = relu(xb@lin0wt + lin0b) -> bufAb (bf16, MFMA)
  bgemm_k<2,true,false,true><<<nGB, 256, 0, stream>>>(xb, lin0wt, lin0b, nullptr, nullptr, bufAb, Mn, 0.f);
  // 7) layer 0: gather agg (bf16) from bufAb; hnext -> bufCb (bf16, MFMA resid)
  agg_gather_k<<<(Mn+3)/4, 256, 0, stream>>>(bufAb, off, csr_src, csr_w, deg, aggb, Mn);
  bgemm_k<2,true,true,true><<<nGB, 256, 0, stream>>>(aggb, cw1t0, nullptr, aggb, nullptr, bufCb, Mn, beta0);
  // 8) layer 1: gather agg from bufCb; hnext -> bufBb (bf16, MFMA resid)
  agg_gather_k<<<(Mn+3)/4, 256, 0, stream>>>(bufCb, off, csr_src, csr_w, deg, aggb, Mn);
  bgemm_k<2,true,true,true><<<nGB, 256, 0, stream>>>(aggb, cw1t1, nullptr, aggb, nullptr, bufBb, Mn, beta1);
  // 9) out = bufBb @ lin1wt + lin1b (fp32 out, MFMA)
  bgemm_k<1,false,false,false><<<nGB, 256, 0, stream>>>(bufBb, lin1wt, lin1b, nullptr, out, nullptr, Mn, 0.f);
}